// Round 18
// baseline (310.728 us; speedup 1.0000x reference)
//
#include <hip/hip_runtime.h>
#include <hip/hip_bf16.h>

typedef unsigned short u16;
typedef unsigned int   u32;
typedef _Float16 f16;
typedef __attribute__((ext_vector_type(8))) _Float16 f16x8;
typedef __attribute__((ext_vector_type(4))) _Float16 f16x4;
typedef __attribute__((ext_vector_type(4))) float    f32x4;
typedef __attribute__((ext_vector_type(8))) unsigned short u16x8;

#define BATCH 4
#define CH 512
#define NN 4096
#define CQ 64
#define LOG2E 1.44269504f

__device__ __forceinline__ float bf2f(u16 v) {
    union { unsigned int u; float f; } x; x.u = ((unsigned int)v) << 16; return x.f;
}

// tiled P layout: element (j,i) -> (j>>4)*65536 + (i>>3)*128 + (j&15)*8 + (i&7)
__device__ __forceinline__ size_t stt_idx(int j, int i) {
    return (size_t)(j >> 4) * 65536 + (size_t)((i >> 3) * 128 + (j & 15) * 8 + (i & 7));
}

// async global->LDS, 16B per lane; LDS dest = wave-uniform base + lane*16
__device__ __forceinline__ void glds16(const f16* g, f16* s) {
    __builtin_amdgcn_global_load_lds(
        (const __attribute__((address_space(1))) void*)g,
        (__attribute__((address_space(3))) void*)s, 16, 0, 0);
}

// ---------------------------------------------------------------------------
// Input dtype detector: 0 = fp32 inputs, 1 = bf16 inputs.
// ---------------------------------------------------------------------------
__global__ __launch_bounds__(64) void detect_kernel(const u32* __restrict__ xw,
                                                    int* __restrict__ flag)
{
    const u32 w  = xw[threadIdx.x];
    const u32 ex = (w >> 23) & 0xFFu;
    const int plausible = (ex >= 100u && ex <= 132u) ? 1 : 0;
    const unsigned long long m = __ballot(plausible);
    if (threadIdx.x == 0) flag[0] = (__popcll(m) >= 48) ? 0 : 1;
}

// ---------------------------------------------------------------------------
// W concat convert: Wc[640][512] f16 from Wq/Wk/Wv (fp32 or bf16).
// ---------------------------------------------------------------------------
__global__ __launch_bounds__(256) void wconv_kernel(
    const void* __restrict__ Wq, const void* __restrict__ Wk,
    const void* __restrict__ Wv, const int* __restrict__ flag,
    f16* __restrict__ Wc)
{
    const int isbf = *flag;
    const int row = blockIdx.x;           // 0..639
    const int t   = threadIdx.x;
    const void* src; int r;
    if (row < 64)       { src = Wq; r = row; }
    else if (row < 128) { src = Wk; r = row - 64; }
    else                { src = Wv; r = row - 128; }
    f16 v0, v1;
    if (isbf) {
        const u16* p = (const u16*)src + (size_t)r * CH + 2 * t;
        v0 = (f16)bf2f(p[0]); v1 = (f16)bf2f(p[1]);
    } else {
        const float* p = (const float*)src + (size_t)r * CH + 2 * t;
        v0 = (f16)p[0]; v1 = (f16)p[1];
    }
    Wc[(size_t)row * CH + 2 * t]     = v0;
    Wc[(size_t)row * CH + 2 * t + 1] = v1;
}

// ---------------------------------------------------------------------------
// x transpose: xT[b][n][c] f16 from x[b][c][n] (fp32 or bf16). 64x64 tiles.
// ---------------------------------------------------------------------------
__global__ __launch_bounds__(256) void xpose_kernel(
    const void* __restrict__ xin, const int* __restrict__ flag,
    f16* __restrict__ xT)
{
    const int isbf = *flag;
    const int n0 = blockIdx.x * 64, c0 = blockIdx.y * 64, b = blockIdx.z;
    const int t  = threadIdx.x;
    __shared__ float Xl[64][65];

    {
        const int row = t >> 2, nc = (t & 3) * 16;
        if (isbf) {
            const u16* p = (const u16*)xin +
                           ((size_t)(b * CH + c0 + row)) * NN + n0 + nc;
            const u16x8 a = *(const u16x8*)p;
            const u16x8 bq = *(const u16x8*)(p + 8);
#pragma unroll
            for (int i = 0; i < 8; ++i) Xl[row][nc + i]     = bf2f(a[i]);
#pragma unroll
            for (int i = 0; i < 8; ++i) Xl[row][nc + 8 + i] = bf2f(bq[i]);
        } else {
            const float* p = (const float*)xin +
                             ((size_t)(b * CH + c0 + row)) * NN + n0 + nc;
            *(f32x4*)&Xl[row][nc]      = *(const f32x4*)(p);
            *(f32x4*)&Xl[row][nc + 4]  = *(const f32x4*)(p + 4);
            *(f32x4*)&Xl[row][nc + 8]  = *(const f32x4*)(p + 8);
            *(f32x4*)&Xl[row][nc + 12] = *(const f32x4*)(p + 12);
        }
    }
    __syncthreads();
    {
        const int nr = t >> 2, cc = (t & 3) * 16;
        f16x8 o0, o1;
#pragma unroll
        for (int i = 0; i < 8; ++i) o0[i] = (f16)Xl[cc + i][nr];
#pragma unroll
        for (int i = 0; i < 8; ++i) o1[i] = (f16)Xl[cc + 8 + i][nr];
        f16* dst = xT + ((size_t)b * NN + n0 + nr) * CH + c0 + cc;
        *(f16x8*)dst       = o0;
        *(f16x8*)(dst + 8) = o1;
    }
}

// ---------------------------------------------------------------------------
// Projection as all-register MFMA GEMM: out[o][n] = sum_c Wc[o][c] xT[n][c].
// ---------------------------------------------------------------------------
__global__ __launch_bounds__(512, 2) void proj_mfma(
    const f16* __restrict__ Wc, const f16* __restrict__ xT,
    f16* __restrict__ fT, f16* __restrict__ gT, f16* __restrict__ hv)
{
    const int o0 = blockIdx.x * 128;      // 0..4 -> 640 rows
    const int n0 = blockIdx.y * 128;
    const int b  = blockIdx.z;
    const int t  = threadIdx.x;
    const int w  = t >> 6, l = t & 63;
    const int j16 = l & 15, h = l >> 4;
    const int ow = w >> 2, nw = w & 3;

    const f16* wp[4];
#pragma unroll
    for (int ot = 0; ot < 4; ++ot)
        wp[ot] = Wc + (size_t)(o0 + 64 * ow + 16 * ot + j16) * CH;
    const f16* xp[2];
#pragma unroll
    for (int bt = 0; bt < 2; ++bt)
        xp[bt] = xT + ((size_t)b * NN + n0 + 32 * nw + 16 * bt + j16) * CH;

    f32x4 acc[4][2];
#pragma unroll
    for (int ot = 0; ot < 4; ++ot)
#pragma unroll
        for (int bt = 0; bt < 2; ++bt)
#pragma unroll
            for (int r = 0; r < 4; ++r) acc[ot][bt][r] = 0.f;

    f16x8 af[2][4], bq[2][2];
#pragma unroll
    for (int ot = 0; ot < 4; ++ot) af[0][ot] = *(const f16x8*)(wp[ot] + 8 * h);
#pragma unroll
    for (int bt = 0; bt < 2; ++bt) bq[0][bt] = *(const f16x8*)(xp[bt] + 8 * h);

    for (int ks = 0; ks < 16; ++ks) {
        const int cur = ks & 1;
        if (ks < 15) {
            const int k1 = (ks + 1) * 32 + 8 * h;
#pragma unroll
            for (int ot = 0; ot < 4; ++ot)
                af[cur ^ 1][ot] = *(const f16x8*)(wp[ot] + k1);
#pragma unroll
            for (int bt = 0; bt < 2; ++bt)
                bq[cur ^ 1][bt] = *(const f16x8*)(xp[bt] + k1);
        }
        __builtin_amdgcn_s_setprio(1);
#pragma unroll
        for (int ot = 0; ot < 4; ++ot)
#pragma unroll
            for (int bt = 0; bt < 2; ++bt)
                acc[ot][bt] = __builtin_amdgcn_mfma_f32_16x16x32_f16(
                                  af[cur][ot], bq[cur][bt], acc[ot][bt], 0, 0, 0);
        __builtin_amdgcn_s_setprio(0);
    }

#pragma unroll
    for (int ot = 0; ot < 4; ++ot)
#pragma unroll
        for (int bt = 0; bt < 2; ++bt)
#pragma unroll
            for (int r = 0; r < 4; ++r) {
                const int o = o0 + 64 * ow + 16 * ot + 4 * h + r;
                const int n = n0 + 32 * nw + 16 * bt + j16;
                const f16 v = (f16)acc[ot][bt][r];
                if (o < CQ) {
                    fT[((size_t)b * NN + n) * CQ + o] = v;
                } else if (o < 2 * CQ) {
                    gT[((size_t)b * NN + n) * CQ + (o - CQ)] = v;
                } else {
                    hv[((size_t)b * CH + (o - 2 * CQ)) * NN + n] = v;
                }
            }
}

// ---------------------------------------------------------------------------
// K1: per 64-i tile: m_t[j] = max_i S*log2e; P_t = exp2(S*log2e - m_t) (f16,
// tiled layout, <=1); mbT[b][itile][j] = m_t; lsum[b][j] += 2^m_t * sum(P).
// ---------------------------------------------------------------------------
__global__ __launch_bounds__(512) void score_kernel(
    const f16* __restrict__ fT, const f16* __restrict__ gT,
    f16* __restrict__ ST, float* __restrict__ lsum, float* __restrict__ mbT,
    int b0)
{
    const int ibk = blockIdx.x;
    const int jbk = blockIdx.y;
    const int bz  = blockIdx.z;
    const int b   = b0 + bz;
    const int t   = threadIdx.x;
    const int w   = t >> 6, l = t & 63;
    const int c16 = l & 15, h = l >> 4;
    const int wr  = w >> 1;
    const int wc  = w & 1;
    const int j0  = jbk * 128 + wr * 32;
    const int i0  = ibk * 128 + wc * 64;
    const int itile = ibk * 2 + wc;

    const f16* fb_ = fT + (size_t)b * NN * CQ;
    const f16* gb_ = gT + (size_t)b * NN * CQ;

    f16x8 ga[2][2], fbr[4][2];
#pragma unroll
    for (int ja = 0; ja < 2; ++ja)
#pragma unroll
        for (int kc = 0; kc < 2; ++kc)
            ga[ja][kc] = *(const f16x8*)(gb_ +
                (size_t)(j0 + 16 * ja + c16) * CQ + 32 * kc + 8 * h);
#pragma unroll
    for (int ii = 0; ii < 4; ++ii)
#pragma unroll
        for (int kc = 0; kc < 2; ++kc)
            fbr[ii][kc] = *(const f16x8*)(fb_ +
                (size_t)(i0 + 16 * ii + c16) * CQ + 32 * kc + 8 * h);

    f32x4 s[2][4];
#pragma unroll
    for (int ja = 0; ja < 2; ++ja)
#pragma unroll
        for (int ii = 0; ii < 4; ++ii)
#pragma unroll
            for (int r = 0; r < 4; ++r) s[ja][ii][r] = 0.f;

#pragma unroll
    for (int ja = 0; ja < 2; ++ja)
#pragma unroll
        for (int ii = 0; ii < 4; ++ii) {
            s[ja][ii] = __builtin_amdgcn_mfma_f32_16x16x32_f16(
                            ga[ja][0], fbr[ii][0], s[ja][ii], 0, 0, 0);
            s[ja][ii] = __builtin_amdgcn_mfma_f32_16x16x32_f16(
                            ga[ja][1], fbr[ii][1], s[ja][ii], 0, 0, 0);
        }

    f16* Sb = ST + (size_t)bz * NN * NN;

#pragma unroll
    for (int ja = 0; ja < 2; ++ja)
#pragma unroll
        for (int r = 0; r < 4; ++r) {
            const int jj = j0 + 16 * ja + 4 * h + r;
            float hx[4];
#pragma unroll
            for (int ii = 0; ii < 4; ++ii) hx[ii] = s[ja][ii][r] * LOG2E;
            float mt = fmaxf(fmaxf(hx[0], hx[1]), fmaxf(hx[2], hx[3]));
            mt = fmaxf(mt, __shfl_xor(mt, 1));
            mt = fmaxf(mt, __shfl_xor(mt, 2));
            mt = fmaxf(mt, __shfl_xor(mt, 4));
            mt = fmaxf(mt, __shfl_xor(mt, 8));
            float rs = 0.f;
#pragma unroll
            for (int ii = 0; ii < 4; ++ii) {
                const float p = exp2f(hx[ii] - mt);
                rs += p;
                Sb[stt_idx(jj, i0 + 16 * ii + c16)] = (f16)p;
            }
            rs += __shfl_xor(rs, 1);
            rs += __shfl_xor(rs, 2);
            rs += __shfl_xor(rs, 4);
            rs += __shfl_xor(rs, 8);
            if (c16 == 0) {
                mbT[((size_t)b * 64 + itile) * NN + jj] = mt;
                atomicAdd(&lsum[(size_t)b * NN + jj], exp2f(mt) * rs);
            }
        }
}

// ---------------------------------------------------------------------------
// fac precompute: facT[bz][it][j] = (f16) 2^(m_t[j] - log2 lsum[j]).
// ---------------------------------------------------------------------------
__global__ __launch_bounds__(256) void fac_kernel(
    const float* __restrict__ lsum, const float* __restrict__ mbT,
    f16* __restrict__ facT, int b0)
{
    const int j  = blockIdx.x * 256 + threadIdx.x;
    const int it = blockIdx.y;
    const int bz = blockIdx.z;
    const int b  = b0 + bz;
    const float lg = __log2f(lsum[(size_t)b * NN + j]);
    const float m  = mbT[((size_t)b * 64 + it) * NN + j];
    facT[((size_t)bz * 64 + it) * NN + j] = (f16)exp2f(m - lg);
}

// ---------------------------------------------------------------------------
// K3 v9: v8 structure with i-step 128 -> 32 steps (half the barriers).
// Tile 256j x 64c, 4 waves, wave 64j x 64c; ring-2 LDS B (32 KB), depth-1
// prefetch with lead = 1 full step (~3000 cy >> 900 cy HBM) so a plain
// __syncthreads at step entry suffices (drain is free given the lead).
// fac loaded per step from global (counted in the same batch).
// Epilogue transpose buffer aliased onto Bs (union smem).
// ---------------------------------------------------------------------------
__global__ __launch_bounds__(256, 2) void pv_kernel(
    const void* __restrict__ xin, const f16* __restrict__ hv,
    const f16* __restrict__ ST, const f16* __restrict__ facT,
    const void* __restrict__ gammap, const int* __restrict__ flag,
    float* __restrict__ out, int b0, int bc)
{
    const int isbf = *flag;
    const int bid  = blockIdx.x;             // 0..128*bc-1
    const int xcd  = bid & 7;
    const int slot = bid >> 3;               // 0..16*bc-1
    const int perb = 8 / bc;
    const int bz   = xcd / perb;
    const int b    = b0 + bz;
    const int idx  = (xcd % perb) * (16 * bc) + slot;   // 0..127
    const int cb   = idx >> 4;               // 0..7  (outer: hv L2 reuse)
    const int jb   = idx & 15;               // 0..15
    const int j0   = jb * 256;
    const int c0   = cb * 64;

    const int t = threadIdx.x;
    const int w = t >> 6, l = t & 63;
    const int l16 = l & 15, h = l >> 4;
    const int jw0 = j0 + w * 64;             // wave-private 64-j slice

    // union LDS: main loop uses Bs (32 KB); epilogue reuses it as Tl (16.6 KB)
    __shared__ __align__(16) unsigned char smem[32768];
    f16   (*Bs)[4][4][64][8] = (f16 (*)[4][4][64][8])smem;  // [ring][ci][ck][l][e]
    float (*Tl)[16][65]      = (float (*)[16][65])smem;     // [wave][cc][jl]

    // A source: tiled ST, per-lane 16B contiguous
    const f16* SA  = ST + (size_t)bz * NN * NN
                   + (size_t)(jw0 >> 4) * 65536 + l16 * 8;
    // B glds source: wave w stages c rows [c0+16w, c0+16w+16)
    const f16* hw_ = hv + (size_t)b * CH * NN
                   + (size_t)(c0 + 16 * w + l16) * NN + 8 * h;
    // fac source: per-lane scalar, j = jw0 + jt*16 + l16
    const f16* Ff  = facT + (size_t)bz * 64 * NN + jw0 + l16;

    f32x4 acc[4][4];                         // [jt][ci], static idx only
#pragma unroll
    for (int jt = 0; jt < 4; ++jt)
#pragma unroll
        for (int ci = 0; ci < 4; ++ci)
#pragma unroll
            for (int r = 0; r < 4; ++r) acc[jt][ci][r] = 0.f;

    f16x8 Aa[4][4], Ab[4][4];                // named A double-buffer [jt][ck]
    f16   Fa[2][4], Fb[2][4];                // named fac dbuf [half][jt]

#define STAGE(R, K)                                                          \
    {                                                                        \
        glds16(hw_ + (K) * 128,      &(*Bs[R])[0][0][0] + (size_t)w * 2048); \
        glds16(hw_ + (K) * 128 + 32, &(*Bs[R])[1][0][0] + (size_t)w * 2048); \
        glds16(hw_ + (K) * 128 + 64, &(*Bs[R])[2][0][0] + (size_t)w * 2048); \
        glds16(hw_ + (K) * 128 + 96, &(*Bs[R])[3][0][0] + (size_t)w * 2048); \
    }

#define LDA_(A, F, K)                                                        \
    {                                                                        \
        _Pragma("unroll")                                                    \
        for (int jt = 0; jt < 4; ++jt) {                                     \
            _Pragma("unroll")                                                \
            for (int ck = 0; ck < 4; ++ck)                                   \
                A[jt][ck] = *(const f16x8*)(SA + (size_t)jt * 65536 +        \
                    ((K) * 16 + ck * 4 + h) * 128);                          \
            F[0][jt] = Ff[(size_t)(2 * (K)) * NN + jt * 16];                 \
            F[1][jt] = Ff[(size_t)(2 * (K) + 1) * NN + jt * 16];             \
        }                                                                    \
    }

#define STEP(K, RCUR, RNXT, A_CUR, F_CUR, A_NXT, F_NXT, DO_PF)               \
    {                                                                        \
        __syncthreads();                                                     \
        if (DO_PF) { STAGE(RNXT, (K) + 1); LDA_(A_NXT, F_NXT, (K) + 1); }    \
        _Pragma("unroll")                                                    \
        for (int ck = 0; ck < 4; ++ck) {                                     \
            f16x8 bf[4];                                                     \
            _Pragma("unroll")                                                \
            for (int ci = 0; ci < 4; ++ci)                                   \
                bf[ci] = *(const f16x8*)&Bs[RCUR][ci][ck][l][0];             \
            __builtin_amdgcn_s_setprio(1);                                   \
            _Pragma("unroll")                                                \
            for (int jt = 0; jt < 4; ++jt) {                                 \
                f16x8 fs;                                                    \
                _Pragma("unroll")                                            \
                for (int e = 0; e < 8; ++e) fs[e] = F_CUR[(ck >> 1)][jt];    \
                const f16x8 pa = A_CUR[jt][ck] * fs;                         \
                _Pragma("unroll")                                            \
                for (int ci = 0; ci < 4; ++ci)                               \
                    acc[jt][ci] = __builtin_amdgcn_mfma_f32_16x16x32_f16(    \
                        pa, bf[ci], acc[jt][ci], 0, 0, 0);                   \
            }                                                                \
            __builtin_amdgcn_s_setprio(0);                                   \
        }                                                                    \
    }

    // ---- prologue: batch 0 ----
    STAGE(0, 0);
    LDA_(Aa, Fa, 0);

    for (int k2 = 0; k2 < 16; ++k2) {
        STEP(2 * k2,     0, 1, Aa, Fa, Ab, Fb, (2 * k2     < 31));
        STEP(2 * k2 + 1, 1, 0, Ab, Fb, Aa, Fa, (2 * k2 + 1 < 31));
    }

    // ---- epilogue: transpose O^T via LDS (aliased), coalesced out+x ----
    __syncthreads();                          // all waves done reading Bs
    float gam;
    if (isbf) gam = bf2f(((const u16*)gammap)[0]);
    else      gam = ((const float*)gammap)[0];

#pragma unroll
    for (int ci = 0; ci < 4; ++ci) {
#pragma unroll
        for (int jt = 0; jt < 4; ++jt)
            *(f32x4*)&Tl[w][l16][jt * 16 + 4 * h] = acc[jt][ci];
        asm volatile("s_waitcnt lgkmcnt(0)" ::: "memory");
#pragma unroll
        for (int cc = 0; cc < 16; ++cc) {
            const int c = c0 + ci * 16 + cc;
            const size_t oidx = ((size_t)b * CH + c) * NN + jw0 + l;
            float xv;
            if (isbf) xv = bf2f(((const u16*)xin)[oidx]);
            else      xv = ((const float*)xin)[oidx];
            out[oidx] = gam * Tl[w][cc][l] + xv;
        }
        asm volatile("s_waitcnt lgkmcnt(0)" ::: "memory");
    }
#undef STAGE
#undef LDA_
#undef STEP
}

// ---------------------------------------------------------------------------
// Fallback flash kernel (round 6, passed) for small ws_size.
// ---------------------------------------------------------------------------
__global__ __launch_bounds__(512, 2) void attn_mfma(
    const void* __restrict__ xin, const f16* __restrict__ fT,
    const f16* __restrict__ gT, const f16* __restrict__ hv,
    const void* __restrict__ gammap, const int* __restrict__ flag,
    float* __restrict__ out)
{
    const int isbf = *flag;
    const int bid  = blockIdx.x;
    const int xcd  = bid & 7, slot = bid >> 3;
    const int b    = xcd >> 1;
    const int jblk = ((xcd & 1) << 6) + slot;
    const int j0   = jblk * 32;
    const int t    = threadIdx.x;
    const int w    = t >> 6;
    const int l    = t & 63;
    const int j16  = l & 15;
    const int h    = l >> 4;

    __shared__ f16   Pp[32 * 256];
    __shared__ float wmax[8][2][16];
    __shared__ float wsum[8][2][16];

    f16x8 gf[2][2];
#pragma unroll
    for (int jb = 0; jb < 2; ++jb)
#pragma unroll
        for (int kc = 0; kc < 2; ++kc)
            gf[jb][kc] = *(const f16x8*)(gT +
                ((size_t)b * NN + j0 + 16 * jb + j16) * CQ + 32 * kc + 8 * h);

    f32x4 oacc[4][2];
#pragma unroll
    for (int cb = 0; cb < 4; ++cb)
#pragma unroll
        for (int jb = 0; jb < 2; ++jb)
#pragma unroll
            for (int r = 0; r < 4; ++r) oacc[cb][jb][r] = 0.f;

    float m_run[2] = {-1e30f, -1e30f};
    float l_run[2] = {0.f, 0.f};

    const f16* fbase = fT + (size_t)b * NN * CQ;
    const f16* hbase = hv + (size_t)b * CH * NN;

    f16x8 fa[2][2];
    {
        const int irow0 = 32 * w + j16;
        fa[0][0] = *(const f16x8*)(fbase + (size_t)irow0 * CQ + 8 * h);
        fa[0][1] = *(const f16x8*)(fbase + (size_t)irow0 * CQ + 32 + 8 * h);
        fa[1][0] = *(const f16x8*)(fbase + (size_t)(irow0 + 16) * CQ + 8 * h);
        fa[1][1] = *(const f16x8*)(fbase + (size_t)(irow0 + 16) * CQ + 32 + 8 * h);
    }
    f16x8 aA[4], aB[4];

#define LDAF(BUF, KC, I0BASE)                                                 \
    {                                                                         \
        _Pragma("unroll")                                                     \
        for (int cb = 0; cb < 4; ++cb)                                        \
            BUF[cb] = *(const f16x8*)(hbase +                                 \
                (size_t)(64 * w + 16 * cb + j16) * NN +                       \
                (I0BASE) + 32 * (KC) + 8 * h);                                \
    }

#define PVSTF(BUF, KC)                                                        \
    {                                                                         \
        const int sw0 = (4 * (KC) + h) ^ j16;                                 \
        const f16x8 pf0 = *(const f16x8*)&Pp[j16 * 256 + sw0 * 8];            \
        const f16x8 pf1 = *(const f16x8*)&Pp[(16 + j16) * 256 + sw0 * 8];     \
        _Pragma("unroll")                                                     \
        for (int cb = 0; cb < 4; ++cb) {                                      \
            oacc[cb][0] = __builtin_amdgcn_mfma_f32_16x16x32_f16(             \
                              BUF[cb], pf0, oacc[cb][0], 0, 0, 0);            \
            oacc[cb][1] = __builtin_amdgcn_mfma_f32_16x16x32_f16(             \
                              BUF[cb], pf1, oacc[cb][1], 0, 0, 0);            \
        }                                                                     \
    }

    LDAF(aA, 0, 0);
    LDAF(aB, 1, 0);

    for (int it = 0; it < 16; ++it) {
        const int i0 = it * 256;

        f32x4 s[2][2];
#pragma unroll
        for (int ib = 0; ib < 2; ++ib)
#pragma unroll
            for (int jb = 0; jb < 2; ++jb)
#pragma unroll
                for (int r = 0; r < 4; ++r) s[ib][jb][r] = 0.f;

#pragma unroll
        for (int ib = 0; ib < 2; ++ib)
#pragma unroll
            for (int jb = 0; jb < 2; ++jb) {
                s[ib][jb] = __builtin_amdgcn_mfma_f32_16x16x32_f16(
                                fa[ib][0], gf[jb][0], s[ib][jb], 0, 0, 0);
                s[ib][jb] = __builtin_amdgcn_mfma_f32_16x16x32_f16(
                                fa[ib][1], gf[jb][1], s[ib][jb], 0, 0, 0);
            }

        float pmax[2];
#pragma unroll
        for (int jb = 0; jb < 2; ++jb) {
            float m0 = fmaxf(fmaxf(s[0][jb][0], s[0][jb][1]),
                             fmaxf(s[0][jb][2], s[0][jb][3]));
            float m1 = fmaxf(fmaxf(s[1][jb][0], s[1][jb][1]),
                             fmaxf(s[1][jb][2], s[1][jb][3]));
            float mm = fmaxf(m0, m1);
            mm = fmaxf(mm, __shfl_xor(mm, 16));
            mm = fmaxf(mm, __shfl_xor(mm, 32));
            pmax[jb] = mm;
        }
        if (h == 0) { wmax[w][0][j16] = pmax[0]; wmax[w][1][j16] = pmax[1]; }
        __syncthreads();

        float m_new[2], sc[2];
#pragma unroll
        for (int jb = 0; jb < 2; ++jb) {
            float tm = wmax[0][jb][j16];
#pragma unroll
            for (int w2 = 1; w2 < 8; ++w2) tm = fmaxf(tm, wmax[w2][jb][j16]);
            m_new[jb] = fmaxf(m_run[jb], tm);
            sc[jb]    = __expf(m_run[jb] - m_new[jb]);
            m_run[jb] = m_new[jb];
        }

        float psum[2] = {0.f, 0.f};
#pragma unroll
        for (int ib = 0; ib < 2; ++ib) {
#pragma unroll
            for (int jb = 0; jb < 2; ++jb) {
                const float p0 = __expf(s[ib][jb][0] - m_new[jb]);
                const float p1 = __expf(s[ib][jb][1] - m_new[jb]);
                const float p2 = __expf(s[ib][jb][2] - m_new[jb]);
                const float p3 = __expf(s[ib][jb][3] - m_new[jb]);
                psum[jb] += (p0 + p1) + (p2 + p3);
                f16x4 v4;
                v4[0] = (f16)p0; v4[1] = (f16)p1; v4[2] = (f16)p2; v4[3] = (f16)p3;
                const int jloc = 16 * jb + j16;
                const int sw   = (4 * w + 2 * ib + (h >> 1)) ^ j16;
                *(f16x4*)&Pp[jloc * 256 + sw * 8 + (h & 1) * 4] = v4;
            }
        }
#pragma unroll
        for (int jb = 0; jb < 2; ++jb) {
            psum[jb] += __shfl_xor(psum[jb], 16);
            psum[jb] += __shfl_xor(psum[jb], 32);
        }
        if (h == 0) { wsum[w][0][j16] = psum[0]; wsum[w][1][j16] = psum[1]; }

#pragma unroll
        for (int cb = 0; cb < 4; ++cb)
#pragma unroll
            for (int jb = 0; jb < 2; ++jb)
#pragma unroll
                for (int r = 0; r < 4; ++r) oacc[cb][jb][r] *= sc[jb];

        __syncthreads();

#pragma unroll
        for (int jb = 0; jb < 2; ++jb) {
            float ts = 0.f;
#pragma unroll
            for (int w2 = 0; w2 < 8; ++w2) ts += wsum[w2][jb][j16];
            l_run[jb] = l_run[jb] * sc[jb] + ts;
        }

        const int i0n = (it < 15) ? (i0 + 256) : 0;
        {
            const int irow0 = i0n + 32 * w + j16;
            fa[0][0] = *(const f16x8*)(fbase + (size_t)irow0 * CQ + 8 * h);
            fa[0][1] = *(const f16x8*)(fbase + (size_t)irow0 * CQ + 32 + 8 * h);
            fa[1][0] = *(const f16x8*)(fbase + (size_t)(irow0 + 16) * CQ + 8 * h);
            fa[1][1] = *(const f16x8*)(fbase + (size_t)(irow0 + 16) * CQ + 32 + 8 * h);
        }
        PVSTF(aA, 0); LDAF(aA, 2, i0);
        PVSTF(aB, 1); LDAF(aB, 3, i0);
        PVSTF(aA, 2); LDAF(aA, 4, i0);
        PVSTF(aB, 3); LDAF(aB, 5, i0);
        PVSTF(aA, 4); LDAF(aA, 6, i0);
        PVSTF(aB, 5); LDAF(aB, 7, i0);
        PVSTF(aA, 6); LDAF(aA, 0, i0n);
        PVSTF(aB, 7); LDAF(aB, 1, i0n);
    }

    float gam;
    if (isbf) gam = bf2f(((const u16*)gammap)[0]);
    else      gam = ((const float*)gammap)[0];

    const float inv0 = gam / l_run[0];
    const float inv1 = gam / l_run[1];

#pragma unroll
    for (int cb = 0; cb < 4; ++cb) {
#pragma unroll
        for (int jb = 0; jb < 2; ++jb) {
            const float invj = jb ? inv1 : inv0;
            const int j = j0 + 16 * jb + j16;
#pragma unroll
            for (int r = 0; r < 4; ++r) {
                const int c = 64 * w + 16 * cb + 4 * h + r;
                const size_t idx = ((size_t)b * CH + c) * NN + j;
                float xv;
                if (isbf) xv = bf2f(((const u16*)xin)[idx]);
                else      xv = ((const float*)xin)[idx];
                out[idx] = oacc[cb][jb][r] * invj + xv;
            }
        }
    }
#undef LDAF
#undef PVSTF
}

extern "C" void kernel_launch(void* const* d_in, const int* in_sizes, int n_in,
                              void* d_out, int out_size, void* d_ws, size_t ws_size,
                              hipStream_t stream)
{
    const size_t off_l  = 256;
    const size_t off_m  = off_l  + (size_t)BATCH * NN * 4;          // lsum 64KB
    const size_t off_fT = off_m  + (size_t)BATCH * NN * 64 * 4;     // mbT 4MB
    const size_t off_gT = off_fT + (size_t)BATCH * NN * CQ * 2;
    const size_t off_hv = off_gT + (size_t)BATCH * NN * CQ * 2;
    const size_t off_xT = off_hv + (size_t)BATCH * CH * NN * 2;
    const size_t off_Wc = off_xT + (size_t)BATCH * NN * CH * 2;     // xT 16MB
    const size_t off_ST = off_Wc + (size_t)640 * CH * 2;            // Wc 0.66MB
    const size_t stN    = (size_t)NN * NN * 2;                      // 33.5MB/batch
    const size_t facN   = (size_t)64 * NN * 2;                      // 512KB/batch

    int*   flag = (int*)d_ws;
    float* lsum = (float*)((char*)d_ws + off_l);
    float* mbT  = (float*)((char*)d_ws + off_m);
    f16*   fT   = (f16*)((char*)d_ws + off_fT);
    f16*   gT   = (f16*)((char*)d_ws + off_gT);
    f16*   hv   = (f16*)((char*)d_ws + off_hv);
    f16*   xT   = (f16*)((char*)d_ws + off_xT);
    f16*   Wc   = (f16*)((char*)d_ws + off_Wc);
    f16*   ST   = (f16*)((char*)d_ws + off_ST);

    int bc = 0;
    if      (ws_size >= off_ST + 4 * (stN + facN)) bc = 4;
    else if (ws_size >= off_ST + 2 * (stN + facN)) bc = 2;
    else if (ws_size >= off_ST + 1 * (stN + facN)) bc = 1;
    f16* facT = (f16*)((char*)d_ws + off_ST + (size_t)bc * stN);

    detect_kernel<<<1, 64, 0, stream>>>((const u32*)d_in[0], flag);
    wconv_kernel<<<640, 256, 0, stream>>>(d_in[1], d_in[2], d_in[3], flag, Wc);
    xpose_kernel<<<dim3(64, 8, BATCH), 256, 0, stream>>>(d_in[0], flag, xT);
    proj_mfma<<<dim3(5, 32, BATCH), 512, 0, stream>>>(Wc, xT, fT, gT, hv);

    if (bc) {
        (void)hipMemsetAsync(lsum, 0, (size_t)BATCH * NN * 4, stream);
        for (int b0 = 0; b0 < BATCH; b0 += bc) {
            dim3 g1(32, 32, bc);
            score_kernel<<<g1, 512, 0, stream>>>(fT, gT, ST, lsum, mbT, b0);
            fac_kernel<<<dim3(16, 64, bc), 256, 0, stream>>>(lsum, mbT, facT, b0);
            pv_kernel<<<128 * bc, 256, 0, stream>>>(d_in[0], hv, ST, facT,
                                                    d_in[4], flag,
                                                    (float*)d_out, b0, bc);
        }
    } else {
        attn_mfma<<<512, 512, 0, stream>>>(d_in[0], fT, gT, hv, d_in[4],
                                           flag, (float*)d_out);
    }
}

// Round 19
// 291.941 us; speedup vs baseline: 1.0644x; 1.0644x over previous
//
#include <hip/hip_runtime.h>
#include <hip/hip_bf16.h>

typedef unsigned short u16;
typedef unsigned int   u32;
typedef _Float16 f16;
typedef __attribute__((ext_vector_type(8))) _Float16 f16x8;
typedef __attribute__((ext_vector_type(4))) _Float16 f16x4;
typedef __attribute__((ext_vector_type(4))) float    f32x4;
typedef __attribute__((ext_vector_type(8))) unsigned short u16x8;

#define BATCH 4
#define CH 512
#define NN 4096
#define CQ 64
#define LOG2E 1.44269504f

__device__ __forceinline__ float bf2f(u16 v) {
    union { unsigned int u; float f; } x; x.u = ((unsigned int)v) << 16; return x.f;
}

// tiled P layout: element (j,i) -> (j>>4)*65536 + (i>>3)*128 + (j&15)*8 + (i&7)
__device__ __forceinline__ size_t stt_idx(int j, int i) {
    return (size_t)(j >> 4) * 65536 + (size_t)((i >> 3) * 128 + (j & 15) * 8 + (i & 7));
}

// async global->LDS, 16B per lane; LDS dest = wave-uniform base + lane*16
__device__ __forceinline__ void glds16(const f16* g, f16* s) {
    __builtin_amdgcn_global_load_lds(
        (const __attribute__((address_space(1))) void*)g,
        (__attribute__((address_space(3))) void*)s, 16, 0, 0);
}

// ---------------------------------------------------------------------------
// Input dtype detector: 0 = fp32 inputs, 1 = bf16 inputs.
// ---------------------------------------------------------------------------
__global__ __launch_bounds__(64) void detect_kernel(const u32* __restrict__ xw,
                                                    int* __restrict__ flag)
{
    const u32 w  = xw[threadIdx.x];
    const u32 ex = (w >> 23) & 0xFFu;
    const int plausible = (ex >= 100u && ex <= 132u) ? 1 : 0;
    const unsigned long long m = __ballot(plausible);
    if (threadIdx.x == 0) flag[0] = (__popcll(m) >= 48) ? 0 : 1;
}

// ---------------------------------------------------------------------------
// W concat convert: Wc[640][512] f16 from Wq/Wk/Wv (fp32 or bf16).
// ---------------------------------------------------------------------------
__global__ __launch_bounds__(256) void wconv_kernel(
    const void* __restrict__ Wq, const void* __restrict__ Wk,
    const void* __restrict__ Wv, const int* __restrict__ flag,
    f16* __restrict__ Wc)
{
    const int isbf = *flag;
    const int row = blockIdx.x;           // 0..639
    const int t   = threadIdx.x;
    const void* src; int r;
    if (row < 64)       { src = Wq; r = row; }
    else if (row < 128) { src = Wk; r = row - 64; }
    else                { src = Wv; r = row - 128; }
    f16 v0, v1;
    if (isbf) {
        const u16* p = (const u16*)src + (size_t)r * CH + 2 * t;
        v0 = (f16)bf2f(p[0]); v1 = (f16)bf2f(p[1]);
    } else {
        const float* p = (const float*)src + (size_t)r * CH + 2 * t;
        v0 = (f16)p[0]; v1 = (f16)p[1];
    }
    Wc[(size_t)row * CH + 2 * t]     = v0;
    Wc[(size_t)row * CH + 2 * t + 1] = v1;
}

// ---------------------------------------------------------------------------
// x transpose: xT[b][n][c] f16 from x[b][c][n] (fp32 or bf16). 64x64 tiles.
// ---------------------------------------------------------------------------
__global__ __launch_bounds__(256) void xpose_kernel(
    const void* __restrict__ xin, const int* __restrict__ flag,
    f16* __restrict__ xT)
{
    const int isbf = *flag;
    const int n0 = blockIdx.x * 64, c0 = blockIdx.y * 64, b = blockIdx.z;
    const int t  = threadIdx.x;
    __shared__ float Xl[64][65];

    {
        const int row = t >> 2, nc = (t & 3) * 16;
        if (isbf) {
            const u16* p = (const u16*)xin +
                           ((size_t)(b * CH + c0 + row)) * NN + n0 + nc;
            const u16x8 a = *(const u16x8*)p;
            const u16x8 bq = *(const u16x8*)(p + 8);
#pragma unroll
            for (int i = 0; i < 8; ++i) Xl[row][nc + i]     = bf2f(a[i]);
#pragma unroll
            for (int i = 0; i < 8; ++i) Xl[row][nc + 8 + i] = bf2f(bq[i]);
        } else {
            const float* p = (const float*)xin +
                             ((size_t)(b * CH + c0 + row)) * NN + n0 + nc;
            *(f32x4*)&Xl[row][nc]      = *(const f32x4*)(p);
            *(f32x4*)&Xl[row][nc + 4]  = *(const f32x4*)(p + 4);
            *(f32x4*)&Xl[row][nc + 8]  = *(const f32x4*)(p + 8);
            *(f32x4*)&Xl[row][nc + 12] = *(const f32x4*)(p + 12);
        }
    }
    __syncthreads();
    {
        const int nr = t >> 2, cc = (t & 3) * 16;
        f16x8 o0, o1;
#pragma unroll
        for (int i = 0; i < 8; ++i) o0[i] = (f16)Xl[cc + i][nr];
#pragma unroll
        for (int i = 0; i < 8; ++i) o1[i] = (f16)Xl[cc + 8 + i][nr];
        f16* dst = xT + ((size_t)b * NN + n0 + nr) * CH + c0 + cc;
        *(f16x8*)dst       = o0;
        *(f16x8*)(dst + 8) = o1;
    }
}

// ---------------------------------------------------------------------------
// Projection as all-register MFMA GEMM: out[o][n] = sum_c Wc[o][c] xT[n][c].
// ---------------------------------------------------------------------------
__global__ __launch_bounds__(512, 2) void proj_mfma(
    const f16* __restrict__ Wc, const f16* __restrict__ xT,
    f16* __restrict__ fT, f16* __restrict__ gT, f16* __restrict__ hv)
{
    const int o0 = blockIdx.x * 128;      // 0..4 -> 640 rows
    const int n0 = blockIdx.y * 128;
    const int b  = blockIdx.z;
    const int t  = threadIdx.x;
    const int w  = t >> 6, l = t & 63;
    const int j16 = l & 15, h = l >> 4;
    const int ow = w >> 2, nw = w & 3;

    const f16* wp[4];
#pragma unroll
    for (int ot = 0; ot < 4; ++ot)
        wp[ot] = Wc + (size_t)(o0 + 64 * ow + 16 * ot + j16) * CH;
    const f16* xp[2];
#pragma unroll
    for (int bt = 0; bt < 2; ++bt)
        xp[bt] = xT + ((size_t)b * NN + n0 + 32 * nw + 16 * bt + j16) * CH;

    f32x4 acc[4][2];
#pragma unroll
    for (int ot = 0; ot < 4; ++ot)
#pragma unroll
        for (int bt = 0; bt < 2; ++bt)
#pragma unroll
            for (int r = 0; r < 4; ++r) acc[ot][bt][r] = 0.f;

    f16x8 af[2][4], bq[2][2];
#pragma unroll
    for (int ot = 0; ot < 4; ++ot) af[0][ot] = *(const f16x8*)(wp[ot] + 8 * h);
#pragma unroll
    for (int bt = 0; bt < 2; ++bt) bq[0][bt] = *(const f16x8*)(xp[bt] + 8 * h);

    for (int ks = 0; ks < 16; ++ks) {
        const int cur = ks & 1;
        if (ks < 15) {
            const int k1 = (ks + 1) * 32 + 8 * h;
#pragma unroll
            for (int ot = 0; ot < 4; ++ot)
                af[cur ^ 1][ot] = *(const f16x8*)(wp[ot] + k1);
#pragma unroll
            for (int bt = 0; bt < 2; ++bt)
                bq[cur ^ 1][bt] = *(const f16x8*)(xp[bt] + k1);
        }
        __builtin_amdgcn_s_setprio(1);
#pragma unroll
        for (int ot = 0; ot < 4; ++ot)
#pragma unroll
            for (int bt = 0; bt < 2; ++bt)
                acc[ot][bt] = __builtin_amdgcn_mfma_f32_16x16x32_f16(
                                  af[cur][ot], bq[cur][bt], acc[ot][bt], 0, 0, 0);
        __builtin_amdgcn_s_setprio(0);
    }

#pragma unroll
    for (int ot = 0; ot < 4; ++ot)
#pragma unroll
        for (int bt = 0; bt < 2; ++bt)
#pragma unroll
            for (int r = 0; r < 4; ++r) {
                const int o = o0 + 64 * ow + 16 * ot + 4 * h + r;
                const int n = n0 + 32 * nw + 16 * bt + j16;
                const f16 v = (f16)acc[ot][bt][r];
                if (o < CQ) {
                    fT[((size_t)b * NN + n) * CQ + o] = v;
                } else if (o < 2 * CQ) {
                    gT[((size_t)b * NN + n) * CQ + (o - CQ)] = v;
                } else {
                    hv[((size_t)b * CH + (o - 2 * CQ)) * NN + n] = v;
                }
            }
}

// ---------------------------------------------------------------------------
// K1: per 64-i tile: m_t[j] = max_i S*log2e; P_t = exp2(S*log2e - m_t) (f16,
// tiled layout, <=1); mbT[b][itile][j] = m_t; lsum[b][j] += 2^m_t * sum(P).
// ---------------------------------------------------------------------------
__global__ __launch_bounds__(512) void score_kernel(
    const f16* __restrict__ fT, const f16* __restrict__ gT,
    f16* __restrict__ ST, float* __restrict__ lsum, float* __restrict__ mbT,
    int b0)
{
    const int ibk = blockIdx.x;
    const int jbk = blockIdx.y;
    const int bz  = blockIdx.z;
    const int b   = b0 + bz;
    const int t   = threadIdx.x;
    const int w   = t >> 6, l = t & 63;
    const int c16 = l & 15, h = l >> 4;
    const int wr  = w >> 1;
    const int wc  = w & 1;
    const int j0  = jbk * 128 + wr * 32;
    const int i0  = ibk * 128 + wc * 64;
    const int itile = ibk * 2 + wc;

    const f16* fb_ = fT + (size_t)b * NN * CQ;
    const f16* gb_ = gT + (size_t)b * NN * CQ;

    f16x8 ga[2][2], fbr[4][2];
#pragma unroll
    for (int ja = 0; ja < 2; ++ja)
#pragma unroll
        for (int kc = 0; kc < 2; ++kc)
            ga[ja][kc] = *(const f16x8*)(gb_ +
                (size_t)(j0 + 16 * ja + c16) * CQ + 32 * kc + 8 * h);
#pragma unroll
    for (int ii = 0; ii < 4; ++ii)
#pragma unroll
        for (int kc = 0; kc < 2; ++kc)
            fbr[ii][kc] = *(const f16x8*)(fb_ +
                (size_t)(i0 + 16 * ii + c16) * CQ + 32 * kc + 8 * h);

    f32x4 s[2][4];
#pragma unroll
    for (int ja = 0; ja < 2; ++ja)
#pragma unroll
        for (int ii = 0; ii < 4; ++ii)
#pragma unroll
            for (int r = 0; r < 4; ++r) s[ja][ii][r] = 0.f;

#pragma unroll
    for (int ja = 0; ja < 2; ++ja)
#pragma unroll
        for (int ii = 0; ii < 4; ++ii) {
            s[ja][ii] = __builtin_amdgcn_mfma_f32_16x16x32_f16(
                            ga[ja][0], fbr[ii][0], s[ja][ii], 0, 0, 0);
            s[ja][ii] = __builtin_amdgcn_mfma_f32_16x16x32_f16(
                            ga[ja][1], fbr[ii][1], s[ja][ii], 0, 0, 0);
        }

    f16* Sb = ST + (size_t)bz * NN * NN;

#pragma unroll
    for (int ja = 0; ja < 2; ++ja)
#pragma unroll
        for (int r = 0; r < 4; ++r) {
            const int jj = j0 + 16 * ja + 4 * h + r;
            float hx[4];
#pragma unroll
            for (int ii = 0; ii < 4; ++ii) hx[ii] = s[ja][ii][r] * LOG2E;
            float mt = fmaxf(fmaxf(hx[0], hx[1]), fmaxf(hx[2], hx[3]));
            mt = fmaxf(mt, __shfl_xor(mt, 1));
            mt = fmaxf(mt, __shfl_xor(mt, 2));
            mt = fmaxf(mt, __shfl_xor(mt, 4));
            mt = fmaxf(mt, __shfl_xor(mt, 8));
            float rs = 0.f;
#pragma unroll
            for (int ii = 0; ii < 4; ++ii) {
                const float p = exp2f(hx[ii] - mt);
                rs += p;
                Sb[stt_idx(jj, i0 + 16 * ii + c16)] = (f16)p;
            }
            rs += __shfl_xor(rs, 1);
            rs += __shfl_xor(rs, 2);
            rs += __shfl_xor(rs, 4);
            rs += __shfl_xor(rs, 8);
            if (c16 == 0) {
                mbT[((size_t)b * 64 + itile) * NN + jj] = mt;
                atomicAdd(&lsum[(size_t)b * NN + jj], exp2f(mt) * rs);
            }
        }
}

// ---------------------------------------------------------------------------
// fac precompute: facT[bz][it][j] = (f16) 2^(m_t[j] - log2 lsum[j]).
// ---------------------------------------------------------------------------
__global__ __launch_bounds__(256) void fac_kernel(
    const float* __restrict__ lsum, const float* __restrict__ mbT,
    f16* __restrict__ facT, int b0)
{
    const int j  = blockIdx.x * 256 + threadIdx.x;
    const int it = blockIdx.y;
    const int bz = blockIdx.z;
    const int b  = b0 + bz;
    const float lg = __log2f(lsum[(size_t)b * NN + j]);
    const float m  = mbT[((size_t)b * 64 + it) * NN + j];
    facT[((size_t)bz * 64 + it) * NN + j] = (f16)exp2f(m - lg);
}

// ---------------------------------------------------------------------------
// K3 v8 (round-17 best, 105.5us): tile 256j x 64c, 4 waves, reuse-4 +
// T3/T4 counted-vmcnt depth-2 pipeline: 3-buffer LDS B-ring + 3 named A-reg
// buffers, prefetch 2 steps ahead; per-step sync = vmcnt(10) + raw s_barrier
// + sched_barrier(0). fac staged to LDS in prologue.
// ---------------------------------------------------------------------------
__global__ __launch_bounds__(256, 2) void pv_kernel(
    const void* __restrict__ xin, const f16* __restrict__ hv,
    const f16* __restrict__ ST, const f16* __restrict__ facT,
    const void* __restrict__ gammap, const int* __restrict__ flag,
    float* __restrict__ out, int b0, int bc)
{
    const int isbf = *flag;
    const int bid  = blockIdx.x;             // 0..128*bc-1
    const int xcd  = bid & 7;
    const int slot = bid >> 3;               // 0..16*bc-1
    const int perb = 8 / bc;
    const int bz   = xcd / perb;
    const int b    = b0 + bz;
    const int idx  = (xcd % perb) * (16 * bc) + slot;   // 0..127
    const int cb   = idx >> 4;               // 0..7  (outer: hv L2 reuse)
    const int jb   = idx & 15;               // 0..15
    const int j0   = jb * 256;
    const int c0   = cb * 64;

    const int t = threadIdx.x;
    const int w = t >> 6, l = t & 63;
    const int l16 = l & 15, h = l >> 4;
    const int jw0 = j0 + w * 64;             // wave-private 64-j slice

    __shared__ f16   Bs[3][4][2][64][8];     // 24 KB: 3-ring hv tile
    __shared__ f16   Fl[4][64][64];          // 32 KB: fac [wave][it][jloc]
    __shared__ float Tl[4][16][65];          // 16.6 KB epilogue transpose

    // A source: tiled ST, per-lane 16B contiguous
    const f16* SA  = ST + (size_t)bz * NN * NN
                   + (size_t)(jw0 >> 4) * 65536 + l16 * 8;
    // B glds source: wave w stages c rows [c0+16w, c0+16w+16)
    const f16* hw_ = hv + (size_t)b * CH * NN
                   + (size_t)(c0 + 16 * w + l16) * NN + 8 * h;
    // fac staging source (per-lane 16B of row l>>3)
    const f16* Ff8 = facT + (size_t)bz * 64 * NN
                   + (size_t)(l >> 3) * NN + jw0 + (l & 7) * 8;

    f32x4 acc[4][4];                         // [jt][ct], static idx only
#pragma unroll
    for (int jt = 0; jt < 4; ++jt)
#pragma unroll
        for (int ct = 0; ct < 4; ++ct)
#pragma unroll
            for (int r = 0; r < 4; ++r) acc[jt][ct][r] = 0.f;

    f16x8 A0[4][2], A1[4][2], A2[4][2];      // named A triple-buffer

#define STAGE(R, K)                                                          \
    {                                                                        \
        glds16(hw_ + (K) * 64,      &Bs[R][w][0][0][0]);                     \
        glds16(hw_ + (K) * 64 + 32, &Bs[R][w][1][0][0]);                     \
    }

#define LDA_(A, K)                                                           \
    {                                                                        \
        _Pragma("unroll")                                                    \
        for (int jt = 0; jt < 4; ++jt)                                       \
            _Pragma("unroll")                                                \
            for (int ck = 0; ck < 2; ++ck)                                   \
                A[jt][ck] = *(const f16x8*)(SA + (size_t)jt * 65536 +        \
                    ((K) * 8 + ck * 4 + h) * 128);                           \
    }

// entry: wait consumed batch (10 ops), barrier, pin; then prefetch k+2,
// then fac (LDS) + B (LDS) + MFMA.
#define STEP(K, RCUR, RNXT, A_CUR, A_NXT, NSTR, DO_PF)                       \
    {                                                                        \
        asm volatile("s_waitcnt vmcnt(" NSTR ")" ::: "memory");              \
        __builtin_amdgcn_s_barrier();                                        \
        __builtin_amdgcn_sched_barrier(0);                                   \
        if (DO_PF) { STAGE(RNXT, (K) + 2); LDA_(A_NXT, (K) + 2); }           \
        f16 facs[4];                                                         \
        _Pragma("unroll")                                                    \
        for (int jt = 0; jt < 4; ++jt) facs[jt] = Fl[w][(K)][jt * 16 + l16]; \
        _Pragma("unroll")                                                    \
        for (int ck = 0; ck < 2; ++ck) {                                     \
            f16x8 bf[4];                                                     \
            _Pragma("unroll")                                                \
            for (int ci = 0; ci < 4; ++ci)                                   \
                bf[ci] = *(const f16x8*)&Bs[RCUR][ci][ck][l][0];             \
            __builtin_amdgcn_s_setprio(1);                                   \
            _Pragma("unroll")                                                \
            for (int jt = 0; jt < 4; ++jt) {                                 \
                f16x8 fs;                                                    \
                _Pragma("unroll")                                            \
                for (int e = 0; e < 8; ++e) fs[e] = facs[jt];                \
                const f16x8 pa = A_CUR[jt][ck] * fs;                         \
                _Pragma("unroll")                                            \
                for (int ci = 0; ci < 4; ++ci)                               \
                    acc[jt][ci] = __builtin_amdgcn_mfma_f32_16x16x32_f16(    \
                        pa, bf[ci], acc[jt][ci], 0, 0, 0);                   \
            }                                                                \
            __builtin_amdgcn_s_setprio(0);                                   \
        }                                                                    \
    }

    // ---- prologue: fac slice (8 glds) + batches 0,1 (10 ops each) ----
#pragma unroll
    for (int q = 0; q < 8; ++q)
        glds16(Ff8 + (size_t)(8 * q) * NN, &Fl[w][8 * q][0]);
    STAGE(0, 0); LDA_(A0, 0);
    STAGE(1, 1); LDA_(A1, 1);
    // step 0's entry vmcnt(10) retires Fl(8)+batch0(10), leaves batch1.

    for (int k3 = 0; k3 < 21; ++k3) {
        const int k0 = 3 * k3;
        STEP(k0,     0, 2, A0, A2, "10", (k0     < 62));
        STEP(k0 + 1, 1, 0, A1, A0, "10", (k0 + 1 < 62));
        STEP(k0 + 2, 2, 1, A2, A1, "10", (k0 + 2 < 62));
    }
    STEP(63, 0, 1, A0, A1, "0", 0);

    // ---- epilogue: transpose O^T via LDS, out = gamma*O + x (coalesced) ----
    float gam;
    if (isbf) gam = bf2f(((const u16*)gammap)[0]);
    else      gam = ((const float*)gammap)[0];

#pragma unroll
    for (int ct = 0; ct < 4; ++ct) {
#pragma unroll
        for (int jt = 0; jt < 4; ++jt)
            *(f32x4*)&Tl[w][l16][jt * 16 + 4 * h] = acc[jt][ct];
        asm volatile("s_waitcnt lgkmcnt(0)" ::: "memory");
#pragma unroll
        for (int cc = 0; cc < 16; ++cc) {
            const int c = c0 + ct * 16 + cc;
            const size_t oidx = ((size_t)b * CH + c) * NN + jw0 + l;
            float xv;
            if (isbf) xv = bf2f(((const u16*)xin)[oidx]);
            else      xv = ((const float*)xin)[oidx];
            out[oidx] = gam * Tl[w][cc][l] + xv;
        }
        asm volatile("s_waitcnt lgkmcnt(0)" ::: "memory");
    }
#undef STAGE
#undef LDA_
#undef STEP
}

// ---------------------------------------------------------------------------
// Fallback flash kernel (round 6, passed) for small ws_size.
// ---------------------------------------------------------------------------
__global__ __launch_bounds__(512, 2) void attn_mfma(
    const void* __restrict__ xin, const f16* __restrict__ fT,
    const f16* __restrict__ gT, const f16* __restrict__ hv,
    const void* __restrict__ gammap, const int* __restrict__ flag,
    float* __restrict__ out)
{
    const int isbf = *flag;
    const int bid  = blockIdx.x;
    const int xcd  = bid & 7, slot = bid >> 3;
    const int b    = xcd >> 1;
    const int jblk = ((xcd & 1) << 6) + slot;
    const int j0   = jblk * 32;
    const int t    = threadIdx.x;
    const int w    = t >> 6;
    const int l    = t & 63;
    const int j16  = l & 15;
    const int h    = l >> 4;

    __shared__ f16   Pp[32 * 256];
    __shared__ float wmax[8][2][16];
    __shared__ float wsum[8][2][16];

    f16x8 gf[2][2];
#pragma unroll
    for (int jb = 0; jb < 2; ++jb)
#pragma unroll
        for (int kc = 0; kc < 2; ++kc)
            gf[jb][kc] = *(const f16x8*)(gT +
                ((size_t)b * NN + j0 + 16 * jb + j16) * CQ + 32 * kc + 8 * h);

    f32x4 oacc[4][2];
#pragma unroll
    for (int cb = 0; cb < 4; ++cb)
#pragma unroll
        for (int jb = 0; jb < 2; ++jb)
#pragma unroll
            for (int r = 0; r < 4; ++r) oacc[cb][jb][r] = 0.f;

    float m_run[2] = {-1e30f, -1e30f};
    float l_run[2] = {0.f, 0.f};

    const f16* fbase = fT + (size_t)b * NN * CQ;
    const f16* hbase = hv + (size_t)b * CH * NN;

    f16x8 fa[2][2];
    {
        const int irow0 = 32 * w + j16;
        fa[0][0] = *(const f16x8*)(fbase + (size_t)irow0 * CQ + 8 * h);
        fa[0][1] = *(const f16x8*)(fbase + (size_t)irow0 * CQ + 32 + 8 * h);
        fa[1][0] = *(const f16x8*)(fbase + (size_t)(irow0 + 16) * CQ + 8 * h);
        fa[1][1] = *(const f16x8*)(fbase + (size_t)(irow0 + 16) * CQ + 32 + 8 * h);
    }
    f16x8 aA[4], aB[4];

#define LDAF(BUF, KC, I0BASE)                                                 \
    {                                                                         \
        _Pragma("unroll")                                                     \
        for (int cb = 0; cb < 4; ++cb)                                        \
            BUF[cb] = *(const f16x8*)(hbase +                                 \
                (size_t)(64 * w + 16 * cb + j16) * NN +                       \
                (I0BASE) + 32 * (KC) + 8 * h);                                \
    }

#define PVSTF(BUF, KC)                                                        \
    {                                                                         \
        const int sw0 = (4 * (KC) + h) ^ j16;                                 \
        const f16x8 pf0 = *(const f16x8*)&Pp[j16 * 256 + sw0 * 8];            \
        const f16x8 pf1 = *(const f16x8*)&Pp[(16 + j16) * 256 + sw0 * 8];     \
        _Pragma("unroll")                                                     \
        for (int cb = 0; cb < 4; ++cb) {                                      \
            oacc[cb][0] = __builtin_amdgcn_mfma_f32_16x16x32_f16(             \
                              BUF[cb], pf0, oacc[cb][0], 0, 0, 0);            \
            oacc[cb][1] = __builtin_amdgcn_mfma_f32_16x16x32_f16(             \
                              BUF[cb], pf1, oacc[cb][1], 0, 0, 0);            \
        }                                                                     \
    }

    LDAF(aA, 0, 0);
    LDAF(aB, 1, 0);

    for (int it = 0; it < 16; ++it) {
        const int i0 = it * 256;

        f32x4 s[2][2];
#pragma unroll
        for (int ib = 0; ib < 2; ++ib)
#pragma unroll
            for (int jb = 0; jb < 2; ++jb)
#pragma unroll
                for (int r = 0; r < 4; ++r) s[ib][jb][r] = 0.f;

#pragma unroll
        for (int ib = 0; ib < 2; ++ib)
#pragma unroll
            for (int jb = 0; jb < 2; ++jb) {
                s[ib][jb] = __builtin_amdgcn_mfma_f32_16x16x32_f16(
                                fa[ib][0], gf[jb][0], s[ib][jb], 0, 0, 0);
                s[ib][jb] = __builtin_amdgcn_mfma_f32_16x16x32_f16(
                                fa[ib][1], gf[jb][1], s[ib][jb], 0, 0, 0);
            }

        float pmax[2];
#pragma unroll
        for (int jb = 0; jb < 2; ++jb) {
            float m0 = fmaxf(fmaxf(s[0][jb][0], s[0][jb][1]),
                             fmaxf(s[0][jb][2], s[0][jb][3]));
            float m1 = fmaxf(fmaxf(s[1][jb][0], s[1][jb][1]),
                             fmaxf(s[1][jb][2], s[1][jb][3]));
            float mm = fmaxf(m0, m1);
            mm = fmaxf(mm, __shfl_xor(mm, 16));
            mm = fmaxf(mm, __shfl_xor(mm, 32));
            pmax[jb] = mm;
        }
        if (h == 0) { wmax[w][0][j16] = pmax[0]; wmax[w][1][j16] = pmax[1]; }
        __syncthreads();

        float m_new[2], sc[2];
#pragma unroll
        for (int jb = 0; jb < 2; ++jb) {
            float tm = wmax[0][jb][j16];
#pragma unroll
            for (int w2 = 1; w2 < 8; ++w2) tm = fmaxf(tm, wmax[w2][jb][j16]);
            m_new[jb] = fmaxf(m_run[jb], tm);
            sc[jb]    = __expf(m_run[jb] - m_new[jb]);
            m_run[jb] = m_new[jb];
        }

        float psum[2] = {0.f, 0.f};
#pragma unroll
        for (int ib = 0; ib < 2; ++ib) {
#pragma unroll
            for (int jb = 0; jb < 2; ++jb) {
                const float p0 = __expf(s[ib][jb][0] - m_new[jb]);
                const float p1 = __expf(s[ib][jb][1] - m_new[jb]);
                const float p2 = __expf(s[ib][jb][2] - m_new[jb]);
                const float p3 = __expf(s[ib][jb][3] - m_new[jb]);
                psum[jb] += (p0 + p1) + (p2 + p3);
                f16x4 v4;
                v4[0] = (f16)p0; v4[1] = (f16)p1; v4[2] = (f16)p2; v4[3] = (f16)p3;
                const int jloc = 16 * jb + j16;
                const int sw   = (4 * w + 2 * ib + (h >> 1)) ^ j16;
                *(f16x4*)&Pp[jloc * 256 + sw * 8 + (h & 1) * 4] = v4;
            }
        }
#pragma unroll
        for (int jb = 0; jb < 2; ++jb) {
            psum[jb] += __shfl_xor(psum[jb], 16);
            psum[jb] += __shfl_xor(psum[jb], 32);
        }
        if (h == 0) { wsum[w][0][j16] = psum[0]; wsum[w][1][j16] = psum[1]; }

#pragma unroll
        for (int cb = 0; cb < 4; ++cb)
#pragma unroll
            for (int jb = 0; jb < 2; ++jb)
#pragma unroll
                for (int r = 0; r < 4; ++r) oacc[cb][jb][r] *= sc[jb];

        __syncthreads();

#pragma unroll
        for (int jb = 0; jb < 2; ++jb) {
            float ts = 0.f;
#pragma unroll
            for (int w2 = 0; w2 < 8; ++w2) ts += wsum[w2][jb][j16];
            l_run[jb] = l_run[jb] * sc[jb] + ts;
        }

        const int i0n = (it < 15) ? (i0 + 256) : 0;
        {
            const int irow0 = i0n + 32 * w + j16;
            fa[0][0] = *(const f16x8*)(fbase + (size_t)irow0 * CQ + 8 * h);
            fa[0][1] = *(const f16x8*)(fbase + (size_t)irow0 * CQ + 32 + 8 * h);
            fa[1][0] = *(const f16x8*)(fbase + (size_t)(irow0 + 16) * CQ + 8 * h);
            fa[1][1] = *(const f16x8*)(fbase + (size_t)(irow0 + 16) * CQ + 32 + 8 * h);
        }
        PVSTF(aA, 0); LDAF(aA, 2, i0);
        PVSTF(aB, 1); LDAF(aB, 3, i0);
        PVSTF(aA, 2); LDAF(aA, 4, i0);
        PVSTF(aB, 3); LDAF(aB, 5, i0);
        PVSTF(aA, 4); LDAF(aA, 6, i0);
        PVSTF(aB, 5); LDAF(aB, 7, i0);
        PVSTF(aA, 6); LDAF(aA, 0, i0n);
        PVSTF(aB, 7); LDAF(aB, 1, i0n);
    }

    float gam;
    if (isbf) gam = bf2f(((const u16*)gammap)[0]);
    else      gam = ((const float*)gammap)[0];

    const float inv0 = gam / l_run[0];
    const float inv1 = gam / l_run[1];

#pragma unroll
    for (int cb = 0; cb < 4; ++cb) {
#pragma unroll
        for (int jb = 0; jb < 2; ++jb) {
            const float invj = jb ? inv1 : inv0;
            const int j = j0 + 16 * jb + j16;
#pragma unroll
            for (int r = 0; r < 4; ++r) {
                const int c = 64 * w + 16 * cb + 4 * h + r;
                const size_t idx = ((size_t)b * CH + c) * NN + j;
                float xv;
                if (isbf) xv = bf2f(((const u16*)xin)[idx]);
                else      xv = ((const float*)xin)[idx];
                out[idx] = oacc[cb][jb][r] * invj + xv;
            }
        }
    }
#undef LDAF
#undef PVSTF
}

extern "C" void kernel_launch(void* const* d_in, const int* in_sizes, int n_in,
                              void* d_out, int out_size, void* d_ws, size_t ws_size,
                              hipStream_t stream)
{
    const size_t off_l  = 256;
    const size_t off_m  = off_l  + (size_t)BATCH * NN * 4;          // lsum 64KB
    const size_t off_fT = off_m  + (size_t)BATCH * NN * 64 * 4;     // mbT 4MB
    const size_t off_gT = off_fT + (size_t)BATCH * NN * CQ * 2;
    const size_t off_hv = off_gT + (size_t)BATCH * NN * CQ * 2;
    const size_t off_xT = off_hv + (size_t)BATCH * CH * NN * 2;
    const size_t off_Wc = off_xT + (size_t)BATCH * NN * CH * 2;     // xT 16MB
    const size_t off_ST = off_Wc + (size_t)640 * CH * 2;            // Wc 0.66MB
    const size_t stN    = (size_t)NN * NN * 2;                      // 33.5MB/batch
    const size_t facN   = (size_t)64 * NN * 2;                      // 512KB/batch

    int*   flag = (int*)d_ws;
    float* lsum = (float*)((char*)d_ws + off_l);
    float* mbT  = (float*)((char*)d_ws + off_m);
    f16*   fT   = (f16*)((char*)d_ws + off_fT);
    f16*   gT   = (f16*)((char*)d_ws + off_gT);
    f16*   hv   = (f16*)((char*)d_ws + off_hv);
    f16*   xT   = (f16*)((char*)d_ws + off_xT);
    f16*   Wc   = (f16*)((char*)d_ws + off_Wc);
    f16*   ST   = (f16*)((char*)d_ws + off_ST);

    int bc = 0;
    if      (ws_size >= off_ST + 4 * (stN + facN)) bc = 4;
    else if (ws_size >= off_ST + 2 * (stN + facN)) bc = 2;
    else if (ws_size >= off_ST + 1 * (stN + facN)) bc = 1;
    f16* facT = (f16*)((char*)d_ws + off_ST + (size_t)bc * stN);

    detect_kernel<<<1, 64, 0, stream>>>((const u32*)d_in[0], flag);
    wconv_kernel<<<640, 256, 0, stream>>>(d_in[1], d_in[2], d_in[3], flag, Wc);
    xpose_kernel<<<dim3(64, 8, BATCH), 256, 0, stream>>>(d_in[0], flag, xT);
    proj_mfma<<<dim3(5, 32, BATCH), 512, 0, stream>>>(Wc, xT, fT, gT, hv);

    if (bc) {
        (void)hipMemsetAsync(lsum, 0, (size_t)BATCH * NN * 4, stream);
        for (int b0 = 0; b0 < BATCH; b0 += bc) {
            dim3 g1(32, 32, bc);
            score_kernel<<<g1, 512, 0, stream>>>(fT, gT, ST, lsum, mbT, b0);
            fac_kernel<<<dim3(16, 64, bc), 256, 0, stream>>>(lsum, mbT, facT, b0);
            pv_kernel<<<128 * bc, 256, 0, stream>>>(d_in[0], hv, ST, facT,
                                                    d_in[4], flag,
                                                    (float*)d_out, b0, bc);
        }
    } else {
        attn_mfma<<<512, 512, 0, stream>>>(d_in[0], fT, gT, hv, d_in[4],
                                           flag, (float*)d_out);
    }
}

// Round 20
// 252.578 us; speedup vs baseline: 1.2302x; 1.1558x over previous
//
#include <hip/hip_runtime.h>
#include <hip/hip_bf16.h>

typedef unsigned short u16;
typedef unsigned int   u32;
typedef _Float16 f16;
typedef __attribute__((ext_vector_type(8))) _Float16 f16x8;
typedef __attribute__((ext_vector_type(4))) _Float16 f16x4;
typedef __attribute__((ext_vector_type(4))) float    f32x4;
typedef __attribute__((ext_vector_type(8))) unsigned short u16x8;

#define BATCH 4
#define CH 512
#define NN 4096
#define CQ 64
#define LOG2E 1.44269504f

__device__ __forceinline__ float bf2f(u16 v) {
    union { unsigned int u; float f; } x; x.u = ((unsigned int)v) << 16; return x.f;
}

// tiled P layout: element (j,i) -> (j>>4)*65536 + (i>>3)*128 + (j&15)*8 + (i&7)
__device__ __forceinline__ size_t stt_idx(int j, int i) {
    return (size_t)(j >> 4) * 65536 + (size_t)((i >> 3) * 128 + (j & 15) * 8 + (i & 7));
}

// async global->LDS, 16B per lane; LDS dest = wave-uniform base + lane*16
__device__ __forceinline__ void glds16(const f16* g, f16* s) {
    __builtin_amdgcn_global_load_lds(
        (const __attribute__((address_space(1))) void*)g,
        (__attribute__((address_space(3))) void*)s, 16, 0, 0);
}

// ---------------------------------------------------------------------------
// Input dtype detector: 0 = fp32 inputs, 1 = bf16 inputs.
// ---------------------------------------------------------------------------
__global__ __launch_bounds__(64) void detect_kernel(const u32* __restrict__ xw,
                                                    int* __restrict__ flag)
{
    const u32 w  = xw[threadIdx.x];
    const u32 ex = (w >> 23) & 0xFFu;
    const int plausible = (ex >= 100u && ex <= 132u) ? 1 : 0;
    const unsigned long long m = __ballot(plausible);
    if (threadIdx.x == 0) flag[0] = (__popcll(m) >= 48) ? 0 : 1;
}

// ---------------------------------------------------------------------------
// W concat convert: Wc[640][512] f16 from Wq/Wk/Wv (fp32 or bf16).
// ---------------------------------------------------------------------------
__global__ __launch_bounds__(256) void wconv_kernel(
    const void* __restrict__ Wq, const void* __restrict__ Wk,
    const void* __restrict__ Wv, const int* __restrict__ flag,
    f16* __restrict__ Wc)
{
    const int isbf = *flag;
    const int row = blockIdx.x;           // 0..639
    const int t   = threadIdx.x;
    const void* src; int r;
    if (row < 64)       { src = Wq; r = row; }
    else if (row < 128) { src = Wk; r = row - 64; }
    else                { src = Wv; r = row - 128; }
    f16 v0, v1;
    if (isbf) {
        const u16* p = (const u16*)src + (size_t)r * CH + 2 * t;
        v0 = (f16)bf2f(p[0]); v1 = (f16)bf2f(p[1]);
    } else {
        const float* p = (const float*)src + (size_t)r * CH + 2 * t;
        v0 = (f16)p[0]; v1 = (f16)p[1];
    }
    Wc[(size_t)row * CH + 2 * t]     = v0;
    Wc[(size_t)row * CH + 2 * t + 1] = v1;
}

// ---------------------------------------------------------------------------
// x transpose: xT[b][n][c] f16 from x[b][c][n] (fp32 or bf16). 64x64 tiles.
// ---------------------------------------------------------------------------
__global__ __launch_bounds__(256) void xpose_kernel(
    const void* __restrict__ xin, const int* __restrict__ flag,
    f16* __restrict__ xT)
{
    const int isbf = *flag;
    const int n0 = blockIdx.x * 64, c0 = blockIdx.y * 64, b = blockIdx.z;
    const int t  = threadIdx.x;
    __shared__ float Xl[64][65];

    {
        const int row = t >> 2, nc = (t & 3) * 16;
        if (isbf) {
            const u16* p = (const u16*)xin +
                           ((size_t)(b * CH + c0 + row)) * NN + n0 + nc;
            const u16x8 a = *(const u16x8*)p;
            const u16x8 bq = *(const u16x8*)(p + 8);
#pragma unroll
            for (int i = 0; i < 8; ++i) Xl[row][nc + i]     = bf2f(a[i]);
#pragma unroll
            for (int i = 0; i < 8; ++i) Xl[row][nc + 8 + i] = bf2f(bq[i]);
        } else {
            const float* p = (const float*)xin +
                             ((size_t)(b * CH + c0 + row)) * NN + n0 + nc;
            *(f32x4*)&Xl[row][nc]      = *(const f32x4*)(p);
            *(f32x4*)&Xl[row][nc + 4]  = *(const f32x4*)(p + 4);
            *(f32x4*)&Xl[row][nc + 8]  = *(const f32x4*)(p + 8);
            *(f32x4*)&Xl[row][nc + 12] = *(const f32x4*)(p + 12);
        }
    }
    __syncthreads();
    {
        const int nr = t >> 2, cc = (t & 3) * 16;
        f16x8 o0, o1;
#pragma unroll
        for (int i = 0; i < 8; ++i) o0[i] = (f16)Xl[cc + i][nr];
#pragma unroll
        for (int i = 0; i < 8; ++i) o1[i] = (f16)Xl[cc + 8 + i][nr];
        f16* dst = xT + ((size_t)b * NN + n0 + nr) * CH + c0 + cc;
        *(f16x8*)dst       = o0;
        *(f16x8*)(dst + 8) = o1;
    }
}

// ---------------------------------------------------------------------------
// Projection as all-register MFMA GEMM: out[o][n] = sum_c Wc[o][c] xT[n][c].
// ---------------------------------------------------------------------------
__global__ __launch_bounds__(512, 2) void proj_mfma(
    const f16* __restrict__ Wc, const f16* __restrict__ xT,
    f16* __restrict__ fT, f16* __restrict__ gT, f16* __restrict__ hv)
{
    const int o0 = blockIdx.x * 128;      // 0..4 -> 640 rows
    const int n0 = blockIdx.y * 128;
    const int b  = blockIdx.z;
    const int t  = threadIdx.x;
    const int w  = t >> 6, l = t & 63;
    const int j16 = l & 15, h = l >> 4;
    const int ow = w >> 2, nw = w & 3;

    const f16* wp[4];
#pragma unroll
    for (int ot = 0; ot < 4; ++ot)
        wp[ot] = Wc + (size_t)(o0 + 64 * ow + 16 * ot + j16) * CH;
    const f16* xp[2];
#pragma unroll
    for (int bt = 0; bt < 2; ++bt)
        xp[bt] = xT + ((size_t)b * NN + n0 + 32 * nw + 16 * bt + j16) * CH;

    f32x4 acc[4][2];
#pragma unroll
    for (int ot = 0; ot < 4; ++ot)
#pragma unroll
        for (int bt = 0; bt < 2; ++bt)
#pragma unroll
            for (int r = 0; r < 4; ++r) acc[ot][bt][r] = 0.f;

    f16x8 af[2][4], bq[2][2];
#pragma unroll
    for (int ot = 0; ot < 4; ++ot) af[0][ot] = *(const f16x8*)(wp[ot] + 8 * h);
#pragma unroll
    for (int bt = 0; bt < 2; ++bt) bq[0][bt] = *(const f16x8*)(xp[bt] + 8 * h);

    for (int ks = 0; ks < 16; ++ks) {
        const int cur = ks & 1;
        if (ks < 15) {
            const int k1 = (ks + 1) * 32 + 8 * h;
#pragma unroll
            for (int ot = 0; ot < 4; ++ot)
                af[cur ^ 1][ot] = *(const f16x8*)(wp[ot] + k1);
#pragma unroll
            for (int bt = 0; bt < 2; ++bt)
                bq[cur ^ 1][bt] = *(const f16x8*)(xp[bt] + k1);
        }
        __builtin_amdgcn_s_setprio(1);
#pragma unroll
        for (int ot = 0; ot < 4; ++ot)
#pragma unroll
            for (int bt = 0; bt < 2; ++bt)
                acc[ot][bt] = __builtin_amdgcn_mfma_f32_16x16x32_f16(
                                  af[cur][ot], bq[cur][bt], acc[ot][bt], 0, 0, 0);
        __builtin_amdgcn_s_setprio(0);
    }

#pragma unroll
    for (int ot = 0; ot < 4; ++ot)
#pragma unroll
        for (int bt = 0; bt < 2; ++bt)
#pragma unroll
            for (int r = 0; r < 4; ++r) {
                const int o = o0 + 64 * ow + 16 * ot + 4 * h + r;
                const int n = n0 + 32 * nw + 16 * bt + j16;
                const f16 v = (f16)acc[ot][bt][r];
                if (o < CQ) {
                    fT[((size_t)b * NN + n) * CQ + o] = v;
                } else if (o < 2 * CQ) {
                    gT[((size_t)b * NN + n) * CQ + (o - CQ)] = v;
                } else {
                    hv[((size_t)b * CH + (o - 2 * CQ)) * NN + n] = v;
                }
            }
}

// ---------------------------------------------------------------------------
// K1 (v2, store-coalesced): S = mfma(A=f, B=g) -> lane holds 4 consecutive i
// at fixed j -> tiled-ST stores become dense f16x4 (8B); per (ja,ii) the wave
// covers a contiguous 512B span. i-reduction = in-lane 16 + shfl 16/32.
// Semantics identical to v1: P_t = exp2(S*log2e - m_t), mbT, lsum.
// ---------------------------------------------------------------------------
__global__ __launch_bounds__(512) void score_kernel(
    const f16* __restrict__ fT, const f16* __restrict__ gT,
    f16* __restrict__ ST, float* __restrict__ lsum, float* __restrict__ mbT,
    int b0)
{
    const int ibk = blockIdx.x;
    const int jbk = blockIdx.y;
    const int bz  = blockIdx.z;
    const int b   = b0 + bz;
    const int t   = threadIdx.x;
    const int w   = t >> 6, l = t & 63;
    const int c16 = l & 15, h = l >> 4;
    const int wr  = w >> 1;
    const int wc  = w & 1;
    const int j0  = jbk * 128 + wr * 32;
    const int i0  = ibk * 128 + wc * 64;
    const int itile = ibk * 2 + wc;

    const f16* fb_ = fT + (size_t)b * NN * CQ;
    const f16* gb_ = gT + (size_t)b * NN * CQ;

    f16x8 ga[2][2], fbr[4][2];
#pragma unroll
    for (int ja = 0; ja < 2; ++ja)
#pragma unroll
        for (int kc = 0; kc < 2; ++kc)
            ga[ja][kc] = *(const f16x8*)(gb_ +
                (size_t)(j0 + 16 * ja + c16) * CQ + 32 * kc + 8 * h);
#pragma unroll
    for (int ii = 0; ii < 4; ++ii)
#pragma unroll
        for (int kc = 0; kc < 2; ++kc)
            fbr[ii][kc] = *(const f16x8*)(fb_ +
                (size_t)(i0 + 16 * ii + c16) * CQ + 32 * kc + 8 * h);

    f32x4 s[2][4];
#pragma unroll
    for (int ja = 0; ja < 2; ++ja)
#pragma unroll
        for (int ii = 0; ii < 4; ++ii)
#pragma unroll
            for (int r = 0; r < 4; ++r) s[ja][ii][r] = 0.f;

    // D[i][j]: A = f rows (i), B = g cols (j); col=lane&15=j_loc, row=4h+r=i_loc
#pragma unroll
    for (int ja = 0; ja < 2; ++ja)
#pragma unroll
        for (int ii = 0; ii < 4; ++ii) {
            s[ja][ii] = __builtin_amdgcn_mfma_f32_16x16x32_f16(
                            fbr[ii][0], ga[ja][0], s[ja][ii], 0, 0, 0);
            s[ja][ii] = __builtin_amdgcn_mfma_f32_16x16x32_f16(
                            fbr[ii][1], ga[ja][1], s[ja][ii], 0, 0, 0);
        }

    f16* Sb = ST + (size_t)bz * NN * NN;

#pragma unroll
    for (int ja = 0; ja < 2; ++ja) {
        const int jj = j0 + 16 * ja + c16;       // this lane's j (fixed)
        float hx[4][4];
        float mt = -3.0e38f;
#pragma unroll
        for (int ii = 0; ii < 4; ++ii)
#pragma unroll
            for (int r = 0; r < 4; ++r) {
                hx[ii][r] = s[ja][ii][r] * LOG2E;
                mt = fmaxf(mt, hx[ii][r]);
            }
        // reduce over h lanes (i-direction): bits 4,5 of lane id
        mt = fmaxf(mt, __shfl_xor(mt, 16));
        mt = fmaxf(mt, __shfl_xor(mt, 32));

        float rs = 0.f;
#pragma unroll
        for (int ii = 0; ii < 4; ++ii) {
            f16x4 p4;
#pragma unroll
            for (int r = 0; r < 4; ++r) {
                const float p = exp2f(hx[ii][r] - mt);
                rs += p;
                p4[r] = (f16)p;
            }
            // i_base = i0+16*ii+4h: 4 consecutive i -> one dense 8B store
            *(f16x4*)&Sb[stt_idx(jj, i0 + 16 * ii + 4 * h)] = p4;
        }
        rs += __shfl_xor(rs, 16);
        rs += __shfl_xor(rs, 32);
        if (h == 0) {
            mbT[((size_t)b * 64 + itile) * NN + jj] = mt;
            atomicAdd(&lsum[(size_t)b * NN + jj], exp2f(mt) * rs);
        }
    }
}

// ---------------------------------------------------------------------------
// fac precompute: facT[bz][it][j] = (f16) 2^(m_t[j] - log2 lsum[j]).
// ---------------------------------------------------------------------------
__global__ __launch_bounds__(256) void fac_kernel(
    const float* __restrict__ lsum, const float* __restrict__ mbT,
    f16* __restrict__ facT, int b0)
{
    const int j  = blockIdx.x * 256 + threadIdx.x;
    const int it = blockIdx.y;
    const int bz = blockIdx.z;
    const int b  = b0 + bz;
    const float lg = __log2f(lsum[(size_t)b * NN + j]);
    const float m  = mbT[((size_t)b * 64 + it) * NN + j];
    facT[((size_t)bz * 64 + it) * NN + j] = (f16)exp2f(m - lg);
}

// ---------------------------------------------------------------------------
// K3 v8 (round-17 best, 105.5us): tile 256j x 64c, 4 waves, reuse-4 +
// T3/T4 counted-vmcnt depth-2 pipeline: 3-buffer LDS B-ring + 3 named A-reg
// buffers, prefetch 2 steps ahead; per-step sync = vmcnt(10) + raw s_barrier
// + sched_barrier(0). fac staged to LDS in prologue.
// ---------------------------------------------------------------------------
__global__ __launch_bounds__(256, 2) void pv_kernel(
    const void* __restrict__ xin, const f16* __restrict__ hv,
    const f16* __restrict__ ST, const f16* __restrict__ facT,
    const void* __restrict__ gammap, const int* __restrict__ flag,
    float* __restrict__ out, int b0, int bc)
{
    const int isbf = *flag;
    const int bid  = blockIdx.x;             // 0..128*bc-1
    const int xcd  = bid & 7;
    const int slot = bid >> 3;               // 0..16*bc-1
    const int perb = 8 / bc;
    const int bz   = xcd / perb;
    const int b    = b0 + bz;
    const int idx  = (xcd % perb) * (16 * bc) + slot;   // 0..127
    const int cb   = idx >> 4;               // 0..7  (outer: hv L2 reuse)
    const int jb   = idx & 15;               // 0..15
    const int j0   = jb * 256;
    const int c0   = cb * 64;

    const int t = threadIdx.x;
    const int w = t >> 6, l = t & 63;
    const int l16 = l & 15, h = l >> 4;
    const int jw0 = j0 + w * 64;             // wave-private 64-j slice

    __shared__ f16   Bs[3][4][2][64][8];     // 24 KB: 3-ring hv tile
    __shared__ f16   Fl[4][64][64];          // 32 KB: fac [wave][it][jloc]
    __shared__ float Tl[4][16][65];          // 16.6 KB epilogue transpose

    // A source: tiled ST, per-lane 16B contiguous
    const f16* SA  = ST + (size_t)bz * NN * NN
                   + (size_t)(jw0 >> 4) * 65536 + l16 * 8;
    // B glds source: wave w stages c rows [c0+16w, c0+16w+16)
    const f16* hw_ = hv + (size_t)b * CH * NN
                   + (size_t)(c0 + 16 * w + l16) * NN + 8 * h;
    // fac staging source (per-lane 16B of row l>>3)
    const f16* Ff8 = facT + (size_t)bz * 64 * NN
                   + (size_t)(l >> 3) * NN + jw0 + (l & 7) * 8;

    f32x4 acc[4][4];                         // [jt][ct], static idx only
#pragma unroll
    for (int jt = 0; jt < 4; ++jt)
#pragma unroll
        for (int ct = 0; ct < 4; ++ct)
#pragma unroll
            for (int r = 0; r < 4; ++r) acc[jt][ct][r] = 0.f;

    f16x8 A0[4][2], A1[4][2], A2[4][2];      // named A triple-buffer

#define STAGE(R, K)                                                          \
    {                                                                        \
        glds16(hw_ + (K) * 64,      &Bs[R][w][0][0][0]);                     \
        glds16(hw_ + (K) * 64 + 32, &Bs[R][w][1][0][0]);                     \
    }

#define LDA_(A, K)                                                           \
    {                                                                        \
        _Pragma("unroll")                                                    \
        for (int jt = 0; jt < 4; ++jt)                                       \
            _Pragma("unroll")                                                \
            for (int ck = 0; ck < 2; ++ck)                                   \
                A[jt][ck] = *(const f16x8*)(SA + (size_t)jt * 65536 +        \
                    ((K) * 8 + ck * 4 + h) * 128);                           \
    }

// entry: wait consumed batch (10 ops), barrier, pin; then prefetch k+2,
// then fac (LDS) + B (LDS) + MFMA.
#define STEP(K, RCUR, RNXT, A_CUR, A_NXT, NSTR, DO_PF)                       \
    {                                                                        \
        asm volatile("s_waitcnt vmcnt(" NSTR ")" ::: "memory");              \
        __builtin_amdgcn_s_barrier();                                        \
        __builtin_amdgcn_sched_barrier(0);                                   \
        if (DO_PF) { STAGE(RNXT, (K) + 2); LDA_(A_NXT, (K) + 2); }           \
        f16 facs[4];                                                         \
        _Pragma("unroll")                                                    \
        for (int jt = 0; jt < 4; ++jt) facs[jt] = Fl[w][(K)][jt * 16 + l16]; \
        _Pragma("unroll")                                                    \
        for (int ck = 0; ck < 2; ++ck) {                                     \
            f16x8 bf[4];                                                     \
            _Pragma("unroll")                                                \
            for (int ci = 0; ci < 4; ++ci)                                   \
                bf[ci] = *(const f16x8*)&Bs[RCUR][ci][ck][l][0];             \
            __builtin_amdgcn_s_setprio(1);                                   \
            _Pragma("unroll")                                                \
            for (int jt = 0; jt < 4; ++jt) {                                 \
                f16x8 fs;                                                    \
                _Pragma("unroll")                                            \
                for (int e = 0; e < 8; ++e) fs[e] = facs[jt];                \
                const f16x8 pa = A_CUR[jt][ck] * fs;                         \
                _Pragma("unroll")                                            \
                for (int ci = 0; ci < 4; ++ci)                               \
                    acc[jt][ci] = __builtin_amdgcn_mfma_f32_16x16x32_f16(    \
                        pa, bf[ci], acc[jt][ci], 0, 0, 0);                   \
            }                                                                \
            __builtin_amdgcn_s_setprio(0);                                   \
        }                                                                    \
    }

    // ---- prologue: fac slice (8 glds) + batches 0,1 (10 ops each) ----
#pragma unroll
    for (int q = 0; q < 8; ++q)
        glds16(Ff8 + (size_t)(8 * q) * NN, &Fl[w][8 * q][0]);
    STAGE(0, 0); LDA_(A0, 0);
    STAGE(1, 1); LDA_(A1, 1);
    // step 0's entry vmcnt(10) retires Fl(8)+batch0(10), leaves batch1.

    for (int k3 = 0; k3 < 21; ++k3) {
        const int k0 = 3 * k3;
        STEP(k0,     0, 2, A0, A2, "10", (k0     < 62));
        STEP(k0 + 1, 1, 0, A1, A0, "10", (k0 + 1 < 62));
        STEP(k0 + 2, 2, 1, A2, A1, "10", (k0 + 2 < 62));
    }
    STEP(63, 0, 1, A0, A1, "0", 0);

    // ---- epilogue: transpose O^T via LDS, out = gamma*O + x (coalesced) ----
    float gam;
    if (isbf) gam = bf2f(((const u16*)gammap)[0]);
    else      gam = ((const float*)gammap)[0];

#pragma unroll
    for (int ct = 0; ct < 4; ++ct) {
#pragma unroll
        for (int jt = 0; jt < 4; ++jt)
            *(f32x4*)&Tl[w][l16][jt * 16 + 4 * h] = acc[jt][ct];
        asm volatile("s_waitcnt lgkmcnt(0)" ::: "memory");
#pragma unroll
        for (int cc = 0; cc < 16; ++cc) {
            const int c = c0 + ct * 16 + cc;
            const size_t oidx = ((size_t)b * CH + c) * NN + jw0 + l;
            float xv;
            if (isbf) xv = bf2f(((const u16*)xin)[oidx]);
            else      xv = ((const float*)xin)[oidx];
            out[oidx] = gam * Tl[w][cc][l] + xv;
        }
        asm volatile("s_waitcnt lgkmcnt(0)" ::: "memory");
    }
#undef STAGE
#undef LDA_
#undef STEP
}

// ---------------------------------------------------------------------------
// Fallback flash kernel (round 6, passed) for small ws_size.
// ---------------------------------------------------------------------------
__global__ __launch_bounds__(512, 2) void attn_mfma(
    const void* __restrict__ xin, const f16* __restrict__ fT,
    const f16* __restrict__ gT, const f16* __restrict__ hv,
    const void* __restrict__ gammap, const int* __restrict__ flag,
    float* __restrict__ out)
{
    const int isbf = *flag;
    const int bid  = blockIdx.x;
    const int xcd  = bid & 7, slot = bid >> 3;
    const int b    = xcd >> 1;
    const int jblk = ((xcd & 1) << 6) + slot;
    const int j0   = jblk * 32;
    const int t    = threadIdx.x;
    const int w    = t >> 6;
    const int l    = t & 63;
    const int j16  = l & 15;
    const int h    = l >> 4;

    __shared__ f16   Pp[32 * 256];
    __shared__ float wmax[8][2][16];
    __shared__ float wsum[8][2][16];

    f16x8 gf[2][2];
#pragma unroll
    for (int jb = 0; jb < 2; ++jb)
#pragma unroll
        for (int kc = 0; kc < 2; ++kc)
            gf[jb][kc] = *(const f16x8*)(gT +
                ((size_t)b * NN + j0 + 16 * jb + j16) * CQ + 32 * kc + 8 * h);

    f32x4 oacc[4][2];
#pragma unroll
    for (int cb = 0; cb < 4; ++cb)
#pragma unroll
        for (int jb = 0; jb < 2; ++jb)
#pragma unroll
            for (int r = 0; r < 4; ++r) oacc[cb][jb][r] = 0.f;

    float m_run[2] = {-1e30f, -1e30f};
    float l_run[2] = {0.f, 0.f};

    const f16* fbase = fT + (size_t)b * NN * CQ;
    const f16* hbase = hv + (size_t)b * CH * NN;

    f16x8 fa[2][2];
    {
        const int irow0 = 32 * w + j16;
        fa[0][0] = *(const f16x8*)(fbase + (size_t)irow0 * CQ + 8 * h);
        fa[0][1] = *(const f16x8*)(fbase + (size_t)irow0 * CQ + 32 + 8 * h);
        fa[1][0] = *(const f16x8*)(fbase + (size_t)(irow0 + 16) * CQ + 8 * h);
        fa[1][1] = *(const f16x8*)(fbase + (size_t)(irow0 + 16) * CQ + 32 + 8 * h);
    }
    f16x8 aA[4], aB[4];

#define LDAF(BUF, KC, I0BASE)                                                 \
    {                                                                         \
        _Pragma("unroll")                                                     \
        for (int cb = 0; cb < 4; ++cb)                                        \
            BUF[cb] = *(const f16x8*)(hbase +                                 \
                (size_t)(64 * w + 16 * cb + j16) * NN +                       \
                (I0BASE) + 32 * (KC) + 8 * h);                                \
    }

#define PVSTF(BUF, KC)                                                        \
    {                                                                         \
        const int sw0 = (4 * (KC) + h) ^ j16;                                 \
        const f16x8 pf0 = *(const f16x8*)&Pp[j16 * 256 + sw0 * 8];            \
        const f16x8 pf1 = *(const f16x8*)&Pp[(16 + j16) * 256 + sw0 * 8];     \
        _Pragma("unroll")                                                     \
        for (int cb = 0; cb < 4; ++cb) {                                      \
            oacc[cb][0] = __builtin_amdgcn_mfma_f32_16x16x32_f16(             \
                              BUF[cb], pf0, oacc[cb][0], 0, 0, 0);            \
            oacc[cb][1] = __builtin_amdgcn_mfma_f32_16x16x32_f16(             \
                              BUF[cb], pf1, oacc[cb][1], 0, 0, 0);            \
        }                                                                     \
    }

    LDAF(aA, 0, 0);
    LDAF(aB, 1, 0);

    for (int it = 0; it < 16; ++it) {
        const int i0 = it * 256;

        f32x4 s[2][2];
#pragma unroll
        for (int ib = 0; ib < 2; ++ib)
#pragma unroll
            for (int jb = 0; jb < 2; ++jb)
#pragma unroll
                for (int r = 0; r < 4; ++r) s[ib][jb][r] = 0.f;

#pragma unroll
        for (int ib = 0; ib < 2; ++ib)
#pragma unroll
            for (int jb = 0; jb < 2; ++jb) {
                s[ib][jb] = __builtin_amdgcn_mfma_f32_16x16x32_f16(
                                fa[ib][0], gf[jb][0], s[ib][jb], 0, 0, 0);
                s[ib][jb] = __builtin_amdgcn_mfma_f32_16x16x32_f16(
                                fa[ib][1], gf[jb][1], s[ib][jb], 0, 0, 0);
            }

        float pmax[2];
#pragma unroll
        for (int jb = 0; jb < 2; ++jb) {
            float m0 = fmaxf(fmaxf(s[0][jb][0], s[0][jb][1]),
                             fmaxf(s[0][jb][2], s[0][jb][3]));
            float m1 = fmaxf(fmaxf(s[1][jb][0], s[1][jb][1]),
                             fmaxf(s[1][jb][2], s[1][jb][3]));
            float mm = fmaxf(m0, m1);
            mm = fmaxf(mm, __shfl_xor(mm, 16));
            mm = fmaxf(mm, __shfl_xor(mm, 32));
            pmax[jb] = mm;
        }
        if (h == 0) { wmax[w][0][j16] = pmax[0]; wmax[w][1][j16] = pmax[1]; }
        __syncthreads();

        float m_new[2], sc[2];
#pragma unroll
        for (int jb = 0; jb < 2; ++jb) {
            float tm = wmax[0][jb][j16];
#pragma unroll
            for (int w2 = 1; w2 < 8; ++w2) tm = fmaxf(tm, wmax[w2][jb][j16]);
            m_new[jb] = fmaxf(m_run[jb], tm);
            sc[jb]    = __expf(m_run[jb] - m_new[jb]);
            m_run[jb] = m_new[jb];
        }

        float psum[2] = {0.f, 0.f};
#pragma unroll
        for (int ib = 0; ib < 2; ++ib) {
#pragma unroll
            for (int jb = 0; jb < 2; ++jb) {
                const float p0 = __expf(s[ib][jb][0] - m_new[jb]);
                const float p1 = __expf(s[ib][jb][1] - m_new[jb]);
                const float p2 = __expf(s[ib][jb][2] - m_new[jb]);
                const float p3 = __expf(s[ib][jb][3] - m_new[jb]);
                psum[jb] += (p0 + p1) + (p2 + p3);
                f16x4 v4;
                v4[0] = (f16)p0; v4[1] = (f16)p1; v4[2] = (f16)p2; v4[3] = (f16)p3;
                const int jloc = 16 * jb + j16;
                const int sw   = (4 * w + 2 * ib + (h >> 1)) ^ j16;
                *(f16x4*)&Pp[jloc * 256 + sw * 8 + (h & 1) * 4] = v4;
            }
        }
#pragma unroll
        for (int jb = 0; jb < 2; ++jb) {
            psum[jb] += __shfl_xor(psum[jb], 16);
            psum[jb] += __shfl_xor(psum[jb], 32);
        }
        if (h == 0) { wsum[w][0][j16] = psum[0]; wsum[w][1][j16] = psum[1]; }

#pragma unroll
        for (int cb = 0; cb < 4; ++cb)
#pragma unroll
            for (int jb = 0; jb < 2; ++jb)
#pragma unroll
                for (int r = 0; r < 4; ++r) oacc[cb][jb][r] *= sc[jb];

        __syncthreads();

#pragma unroll
        for (int jb = 0; jb < 2; ++jb) {
            float ts = 0.f;
#pragma unroll
            for (int w2 = 0; w2 < 8; ++w2) ts += wsum[w2][jb][j16];
            l_run[jb] = l_run[jb] * sc[jb] + ts;
        }

        const int i0n = (it < 15) ? (i0 + 256) : 0;
        {
            const int irow0 = i0n + 32 * w + j16;
            fa[0][0] = *(const f16x8*)(fbase + (size_t)irow0 * CQ + 8 * h);
            fa[0][1] = *(const f16x8*)(fbase + (size_t)irow0 * CQ + 32 + 8 * h);
            fa[1][0] = *(const f16x8*)(fbase + (size_t)(irow0 + 16) * CQ + 8 * h);
            fa[1][1] = *(const f16x8*)(fbase + (size_t)(irow0 + 16) * CQ + 32 + 8 * h);
        }
        PVSTF(aA, 0); LDAF(aA, 2, i0);
        PVSTF(aB, 1); LDAF(aB, 3, i0);
        PVSTF(aA, 2); LDAF(aA, 4, i0);
        PVSTF(aB, 3); LDAF(aB, 5, i0);
        PVSTF(aA, 4); LDAF(aA, 6, i0);
        PVSTF(aB, 5); LDAF(aB, 7, i0);
        PVSTF(aA, 6); LDAF(aA, 0, i0n);
        PVSTF(aB, 7); LDAF(aB, 1, i0n);
    }

    float gam;
    if (isbf) gam = bf2f(((const u16*)gammap)[0]);
    else      gam = ((const float*)gammap)[0];

    const float inv0 = gam / l_run[0];
    const float inv1 = gam / l_run[1];

#pragma unroll
    for (int cb = 0; cb < 4; ++cb) {
#pragma unroll
        for (int jb = 0; jb < 2; ++jb) {
            const float invj = jb ? inv1 : inv0;
            const int j = j0 + 16 * jb + j16;
#pragma unroll
            for (int r = 0; r < 4; ++r) {
                const int c = 64 * w + 16 * cb + 4 * h + r;
                const size_t idx = ((size_t)b * CH + c) * NN + j;
                float xv;
                if (isbf) xv = bf2f(((const u16*)xin)[idx]);
                else      xv = ((const float*)xin)[idx];
                out[idx] = oacc[cb][jb][r] * invj + xv;
            }
        }
    }
#undef LDAF
#undef PVSTF
}

extern "C" void kernel_launch(void* const* d_in, const int* in_sizes, int n_in,
                              void* d_out, int out_size, void* d_ws, size_t ws_size,
                              hipStream_t stream)
{
    const size_t off_l  = 256;
    const size_t off_m  = off_l  + (size_t)BATCH * NN * 4;          // lsum 64KB
    const size_t off_fT = off_m  + (size_t)BATCH * NN * 64 * 4;     // mbT 4MB
    const size_t off_gT = off_fT + (size_t)BATCH * NN * CQ * 2;
    const size_t off_hv = off_gT + (size_t)BATCH * NN * CQ * 2;
    const size_t off_xT = off_hv + (size_t)BATCH * CH * NN * 2;
    const size_t off_Wc = off_xT + (size_t)BATCH * NN * CH * 2;     // xT 16MB
    const size_t off_ST = off_Wc + (size_t)640 * CH * 2;            // Wc 0.66MB
    const size_t stN    = (size_t)NN * NN * 2;                      // 33.5MB/batch
    const size_t facN   = (size_t)64 * NN * 2;                      // 512KB/batch

    int*   flag = (int*)d_ws;
    float* lsum = (float*)((char*)d_ws + off_l);
    float* mbT  = (float*)((char*)d_ws + off_m);
    f16*   fT   = (f16*)((char*)d_ws + off_fT);
    f16*   gT   = (f16*)((char*)d_ws + off_gT);
    f16*   hv   = (f16*)((char*)d_ws + off_hv);
    f16*   xT   = (f16*)((char*)d_ws + off_xT);
    f16*   Wc   = (f16*)((char*)d_ws + off_Wc);
    f16*   ST   = (f16*)((char*)d_ws + off_ST);

    int bc = 0;
    if      (ws_size >= off_ST + 4 * (stN + facN)) bc = 4;
    else if (ws_size >= off_ST + 2 * (stN + facN)) bc = 2;
    else if (ws_size >= off_ST + 1 * (stN + facN)) bc = 1;
    f16* facT = (f16*)((char*)d_ws + off_ST + (size_t)bc * stN);

    detect_kernel<<<1, 64, 0, stream>>>((const u32*)d_in[0], flag);
    wconv_kernel<<<640, 256, 0, stream>>>(d_in[1], d_in[2], d_in[3], flag, Wc);
    xpose_kernel<<<dim3(64, 8, BATCH), 256, 0, stream>>>(d_in[0], flag, xT);
    proj_mfma<<<dim3(5, 32, BATCH), 512, 0, stream>>>(Wc, xT, fT, gT, hv);

    if (bc) {
        (void)hipMemsetAsync(lsum, 0, (size_t)BATCH * NN * 4, stream);
        for (int b0 = 0; b0 < BATCH; b0 += bc) {
            dim3 g1(32, 32, bc);
            score_kernel<<<g1, 512, 0, stream>>>(fT, gT, ST, lsum, mbT, b0);
            fac_kernel<<<dim3(16, 64, bc), 256, 0, stream>>>(lsum, mbT, facT, b0);
            pv_kernel<<<128 * bc, 256, 0, stream>>>(d_in[0], hv, ST, facT,
                                                    d_in[4], flag,
                                                    (float*)d_out, b0, bc);
        }
    } else {
        attn_mfma<<<512, 512, 0, stream>>>(d_in[0], fT, gT, hv, d_in[4],
                                           flag, (float*)d_out);
    }
}